// Round 1
// baseline (478.428 us; speedup 1.0000x reference)
//
#include <hip/hip_runtime.h>
#include <stdint.h>
#include <math.h>

#define NN 8192
#define EE 8192
#define DD 128

// 1 = modern JAX (jax_threefry_partitionable=True, default since ~0.4.36):
//   bits(idx) = o0 ^ o1 of threefry(key, (hi(idx), lo(idx)));
//   split -> subkey j = (o0, o1) of threefry(key, (0, j))
// 0 = legacy counter-halves mode (flip if all outputs mismatch next round)
#define TF_PARTITIONABLE 1

__host__ __device__ inline void tf2x32(uint32_t k0, uint32_t k1, uint32_t c0, uint32_t c1,
                                       uint32_t& o0, uint32_t& o1) {
  uint32_t ks[3] = {k0, k1, 0x1BD11BDAu ^ k0 ^ k1};
  uint32_t x0 = c0 + k0, x1 = c1 + k1;
  const uint32_t rot0[4] = {13u, 15u, 26u, 6u};
  const uint32_t rot1[4] = {17u, 29u, 16u, 24u};
#pragma unroll
  for (int i = 0; i < 5; ++i) {
#pragma unroll
    for (int r = 0; r < 4; ++r) {
      uint32_t d = (i & 1) ? rot1[r] : rot0[r];
      x0 += x1;
      x1 = (x1 << d) | (x1 >> (32u - d));
      x1 ^= x0;
    }
    x0 += ks[(i + 1) % 3];
    x1 += ks[(i + 2) % 3] + (uint32_t)(i + 1);
  }
  o0 = x0; o1 = x1;
}

// random bits for linear index idx of an array of `size` uint32s
__device__ inline uint32_t rbits32(uint32_t k0, uint32_t k1, uint32_t idx, uint32_t size) {
#if TF_PARTITIONABLE
  (void)size;
  uint32_t o0, o1;
  tf2x32(k0, k1, 0u, idx, o0, o1);
  return o0 ^ o1;
#else
  uint32_t half = size >> 1;
  uint32_t o0, o1;
  if (idx < half) { tf2x32(k0, k1, idx, idx + half, o0, o1); return o0; }
  else            { tf2x32(k0, k1, idx - half, idx, o0, o1); return o1; }
#endif
}

__device__ inline float u01(uint32_t b) {
  return __uint_as_float((b >> 9) | 0x3f800000u) - 1.0f;
}

// XLA f32 erf_inv polynomial
__device__ inline float erfinv_f32(float x) {
  float w = -log1pf(-x * x);
  float p;
  if (w < 5.0f) {
    w -= 2.5f;
    p = 2.81022636e-08f;
    p = fmaf(p, w, 3.43273939e-07f);
    p = fmaf(p, w, -3.5233877e-06f);
    p = fmaf(p, w, -4.39150654e-06f);
    p = fmaf(p, w, 0.00021858087f);
    p = fmaf(p, w, -0.00125372503f);
    p = fmaf(p, w, -0.00417768164f);
    p = fmaf(p, w, 0.246640727f);
    p = fmaf(p, w, 1.50140941f);
  } else {
    w = sqrtf(w) - 3.0f;
    p = -0.000200214257f;
    p = fmaf(p, w, 0.000100950558f);
    p = fmaf(p, w, 0.00134934322f);
    p = fmaf(p, w, -0.00367342844f);
    p = fmaf(p, w, 0.00573950773f);
    p = fmaf(p, w, -0.0076224613f);
    p = fmaf(p, w, 0.00943887047f);
    p = fmaf(p, w, 1.00167406f);
    p = fmaf(p, w, 2.83297682f);
  }
  return p * x;
}

// A: per-node gen decision: u(i) < sigmoid(nodes_i . Wp + bp) * anodes_i
__global__ __launch_bounds__(256)
void k_gens(const float* __restrict__ nodes, const float* __restrict__ Wp,
            const float* __restrict__ bp, const float* __restrict__ anodes,
            int* __restrict__ gens, uint32_t kp0, uint32_t kp1) {
  int i = blockIdx.x * 256 + threadIdx.x;
  if (i >= NN) return;
  const float4* row = (const float4*)(nodes + (size_t)i * DD);
  const float4* w = (const float4*)Wp;
  float acc = 0.f;
#pragma unroll
  for (int k = 0; k < DD / 4; ++k) {
    float4 a = row[k], b = w[k];
    acc = fmaf(a.x, b.x, acc); acc = fmaf(a.y, b.y, acc);
    acc = fmaf(a.z, b.z, acc); acc = fmaf(a.w, b.w, acc);
  }
  float prob = 1.0f / (1.0f + expf(-(acc + bp[0])));
  uint32_t b = rbits32(kp0, kp1, (uint32_t)i, NN);
  gens[i] = (u01(b) < prob * anodes[i]) ? 1 : 0;
}

// B: e_active, prefix-scan of gens -> gen_list[rank]=node, scalars, naedges + mask_new
__global__ __launch_bounds__(256)
void k_scan(const float* __restrict__ aedges, const int* __restrict__ gens,
            int* __restrict__ gen_list, float* __restrict__ mask_new,
            float* __restrict__ naedges_out, int* __restrict__ scal) {
  __shared__ float sred[256];
  __shared__ int sscan[256];
  __shared__ int s_eact, s_total;
  int tid = threadIdx.x;

  float s = 0.f;
  for (int j = tid; j < EE; j += 256) s += aedges[j];
  sred[tid] = s; __syncthreads();
  for (int off = 128; off > 0; off >>= 1) {
    if (tid < off) sred[tid] += sred[tid + off];
    __syncthreads();
  }
  if (tid == 0) s_eact = (int)sred[0];
  __syncthreads();
  int e_active = s_eact;

  int base = tid * 32;
  int g[32];
  int loc = 0;
#pragma unroll
  for (int k = 0; k < 32; ++k) { g[k] = gens[base + k]; loc += g[k]; }
  sscan[tid] = loc; __syncthreads();
  if (tid == 0) {
    int run = 0;
    for (int t = 0; t < 256; ++t) { int v = sscan[t]; sscan[t] = run; run += v; }
    s_total = run;
  }
  __syncthreads();
  int total = s_total;
  int rank = sscan[tid];
#pragma unroll
  for (int k = 0; k < 32; ++k) {
    if (g[k]) {
      int slot = e_active + rank;
      if (slot < EE) gen_list[rank] = base + k;
      rank++;
    }
  }
  if (tid == 0) { scal[0] = e_active; scal[1] = total; }

  int allowed = EE - e_active - 1;
  int n_gens = total;
  if (n_gens > allowed) n_gens = allowed;
  if (n_gens < 0) n_gens = 0;

  // naedges = dilate(aedges, n_gens); naedges[E-1]=0; mask_new = naedges*(1-aedges)
  for (int j = tid; j < EE; j += 256) {
    float dil = 0.f;
    for (int k = 0; k <= n_gens; ++k) {
      int jj = j - k;
      if (jj < 0) break;
      if (aedges[jj] > 0.f) { dil = 1.f; break; }
    }
    if (j == EE - 1) dil = 0.f;
    naedges_out[j] = dil;
    mask_new[j] = dil * (1.0f - aedges[j]);
  }
}

// C: categorical(key_samp, scores)[i] for generating rows only
__global__ __launch_bounds__(256)
void k_select(const float* __restrict__ nodes, const float* __restrict__ Wq,
              const float* __restrict__ bq, const float* __restrict__ anodes,
              const int* __restrict__ gens, int* __restrict__ sel,
              uint32_t ks0, uint32_t ks1) {
  int i = blockIdx.x;
  if (gens[i] == 0) return;
  __shared__ float q[DD];
  __shared__ float ni[DD];
  __shared__ float sv[256];
  __shared__ int si[256];
  int tid = threadIdx.x;
  if (tid < DD) ni[tid] = nodes[(size_t)i * DD + tid];
  __syncthreads();
  if (tid < DD) {
    float acc = bq[tid];
    for (int k = 0; k < DD; ++k) acc = fmaf(ni[k], Wq[k * DD + tid], acc);
    q[tid] = acc;
  }
  __syncthreads();

  float bestV = -INFINITY;
  int bestJ = 0;
  for (int j = tid; j < NN; j += 256) {
    const float4* row = (const float4*)(nodes + (size_t)j * DD);
    float acc = 0.f;
#pragma unroll
    for (int k = 0; k < DD / 4; ++k) {
      float4 a = row[k];
      acc = fmaf(a.x, q[4 * k + 0], acc);
      acc = fmaf(a.y, q[4 * k + 1], acc);
      acc = fmaf(a.z, q[4 * k + 2], acc);
      acc = fmaf(a.w, q[4 * k + 3], acc);
    }
    float sc = fminf(fmaxf(acc, -1e4f), 1e4f);
    sc -= (1.0f - anodes[j]) * 1e10f;
    uint32_t b = rbits32(ks0, ks1, (uint32_t)i * NN + (uint32_t)j, 0); // N*N even; size unused in partitionable
    float u = fmaxf(1.17549435e-38f, u01(b));   // uniform(minval=tiny, maxval=1)
    float gmb = -logf(-logf(u));
    float tot = sc + gmb;
    if (tot > bestV) { bestV = tot; bestJ = j; }
  }
  sv[tid] = bestV; si[tid] = bestJ; __syncthreads();
  for (int off = 128; off > 0; off >>= 1) {
    if (tid < off) {
      float v2 = sv[tid + off]; int j2 = si[tid + off];
      if (v2 > sv[tid] || (v2 == sv[tid] && j2 < si[tid])) { sv[tid] = v2; si[tid] = j2; }
    }
    __syncthreads();
  }
  if (tid == 0) sel[i] = si[0];
}

// D: new_edges = edges + normal(key_edges) * mask_new[:,None]
__global__ __launch_bounds__(256)
void k_edges(const float* __restrict__ edges, const float* __restrict__ mask_new,
             float* __restrict__ out, uint32_t ke0, uint32_t ke1) {
  int t = blockIdx.x * 256 + threadIdx.x;
  int idx = t * 4;
  if (idx >= EE * DD) return;
  int e = idx >> 7;
  float m = mask_new[e];
  float4 v = ((const float4*)edges)[t];
  if (m > 0.f) {
    float* pv = &v.x;
#pragma unroll
    for (int k = 0; k < 4; ++k) {
      uint32_t b = rbits32(ke0, ke1, (uint32_t)(idx + k), EE * DD);
      float u = u01(b);
      float x = fmaf(u, 2.0f, -0.99999994f);  // uniform(lo=nextafter(-1,0), hi=1)
      x = fmaxf(-0.99999994f, x);
      float nrm = 1.41421354f * erfinv_f32(x);
      pv[k] += nrm * m;
    }
  }
  ((float4*)out)[t] = v;
}

// Emit nsend / nrec (as float values equal to the reference ints)
__global__ __launch_bounds__(256)
void k_sendrec(const int* __restrict__ send, const int* __restrict__ rec,
               const float* __restrict__ mask_new, const int* __restrict__ gen_list,
               const int* __restrict__ sel, const int* __restrict__ scal,
               float* __restrict__ out_nsend, float* __restrict__ out_nrec) {
  int t = blockIdx.x * 256 + threadIdx.x;
  if (t >= EE) return;
  int e_active = scal[0], total = scal[1];
  float m = mask_new[t];
  float sf = (float)send[t] * (1.0f - m);
  float rf = (float)rec[t] * (1.0f - m);
  int r = t - e_active;
  if (r >= 0 && r < total) {
    int i = gen_list[r];
    sf += (float)i;
    rf += (float)sel[i];
  }
  // reference does .astype(int32): values are exact nonneg ints
  out_nsend[t] = (float)(int)sf;
  out_nrec[t] = (float)(int)rf;
}

extern "C" void kernel_launch(void* const* d_in, const int* in_sizes, int n_in,
                              void* d_out, int out_size, void* d_ws, size_t ws_size,
                              hipStream_t stream) {
  const float* nodes  = (const float*)d_in[0];
  const float* edges  = (const float*)d_in[1];
  const int*   rec    = (const int*)d_in[2];
  const int*   send   = (const int*)d_in[3];
  const float* anodes = (const float*)d_in[4];
  const float* aedges = (const float*)d_in[5];
  const float* Wq     = (const float*)d_in[6];
  const float* bq     = (const float*)d_in[7];
  const float* Wp     = (const float*)d_in[8];
  const float* bp     = (const float*)d_in[9];

  float* out        = (float*)d_out;
  float* out_edges  = out;                    // E*D
  float* out_nsend  = out + (size_t)EE * DD;  // E
  float* out_nrec   = out_nsend + EE;         // E
  float* out_naedge = out_nrec + EE;          // E

  int*   gens     = (int*)d_ws;        // N
  int*   gen_list = gens + NN;         // N
  int*   sel      = gen_list + NN;     // N
  int*   scal     = sel + NN;          // 4
  float* mask_new = (float*)(scal + 4);// E

  // key derivation on host: key(42) = (0,42); split(key,3)
  uint32_t kp0, kp1, ke0, ke1, ks0, ks1;
#if TF_PARTITIONABLE
  tf2x32(0u, 42u, 0u, 0u, kp0, kp1);
  tf2x32(0u, 42u, 0u, 1u, ke0, ke1);
  tf2x32(0u, 42u, 0u, 2u, ks0, ks1);
#else
  // legacy: counts iota(6), halves (0,1,2)/(3,4,5) -> out=[a0,a1,a2,b0,b1,b2], reshape(3,2)
  uint32_t a0, b0, a1, b1, a2, b2;
  tf2x32(0u, 42u, 0u, 3u, a0, b0);
  tf2x32(0u, 42u, 1u, 4u, a1, b1);
  tf2x32(0u, 42u, 2u, 5u, a2, b2);
  kp0 = a0; kp1 = a1;
  ke0 = a2; ke1 = b0;
  ks0 = b1; ks1 = b2;
#endif

  k_gens<<<NN / 256, 256, 0, stream>>>(nodes, Wp, bp, anodes, gens, kp0, kp1);
  k_scan<<<1, 256, 0, stream>>>(aedges, gens, gen_list, mask_new, out_naedge, scal);
  k_select<<<NN, 256, 0, stream>>>(nodes, Wq, bq, anodes, gens, sel, ks0, ks1);
  k_edges<<<(EE * DD / 4) / 256, 256, 0, stream>>>(edges, mask_new, out_edges, ke0, ke1);
  k_sendrec<<<EE / 256, 256, 0, stream>>>(send, rec, mask_new, gen_list, sel, scal,
                                          out_nsend, out_nrec);
}

// Round 2
// 156.454 us; speedup vs baseline: 3.0580x; 3.0580x over previous
//
#include <hip/hip_runtime.h>
#include <stdint.h>
#include <math.h>

#define NN 8192
#define EE 8192
#define DD 128

// modern JAX (jax_threefry_partitionable=True):
//   bits(idx) = o0 ^ o1 of threefry(key, (0, idx));
//   split -> subkey j = (o0, o1) of threefry(key, (0, j))
__host__ __device__ inline void tf2x32(uint32_t k0, uint32_t k1, uint32_t c0, uint32_t c1,
                                       uint32_t& o0, uint32_t& o1) {
  uint32_t ks[3] = {k0, k1, 0x1BD11BDAu ^ k0 ^ k1};
  uint32_t x0 = c0 + k0, x1 = c1 + k1;
  const uint32_t rot0[4] = {13u, 15u, 26u, 6u};
  const uint32_t rot1[4] = {17u, 29u, 16u, 24u};
#pragma unroll
  for (int i = 0; i < 5; ++i) {
#pragma unroll
    for (int r = 0; r < 4; ++r) {
      uint32_t d = (i & 1) ? rot1[r] : rot0[r];
      x0 += x1;
      x1 = (x1 << d) | (x1 >> (32u - d));
      x1 ^= x0;
    }
    x0 += ks[(i + 1) % 3];
    x1 += ks[(i + 2) % 3] + (uint32_t)(i + 1);
  }
  o0 = x0; o1 = x1;
}

__device__ inline uint32_t rbits32(uint32_t k0, uint32_t k1, uint32_t idx) {
  uint32_t o0, o1;
  tf2x32(k0, k1, 0u, idx, o0, o1);
  return o0 ^ o1;
}

__device__ inline float u01(uint32_t b) {
  return __uint_as_float((b >> 9) | 0x3f800000u) - 1.0f;
}

// XLA f32 erf_inv polynomial
__device__ inline float erfinv_f32(float x) {
  float w = -log1pf(-x * x);
  float p;
  if (w < 5.0f) {
    w -= 2.5f;
    p = 2.81022636e-08f;
    p = fmaf(p, w, 3.43273939e-07f);
    p = fmaf(p, w, -3.5233877e-06f);
    p = fmaf(p, w, -4.39150654e-06f);
    p = fmaf(p, w, 0.00021858087f);
    p = fmaf(p, w, -0.00125372503f);
    p = fmaf(p, w, -0.00417768164f);
    p = fmaf(p, w, 0.246640727f);
    p = fmaf(p, w, 1.50140941f);
  } else {
    w = sqrtf(w) - 3.0f;
    p = -0.000200214257f;
    p = fmaf(p, w, 0.000100950558f);
    p = fmaf(p, w, 0.00134934322f);
    p = fmaf(p, w, -0.00367342844f);
    p = fmaf(p, w, 0.00573950773f);
    p = fmaf(p, w, -0.0076224613f);
    p = fmaf(p, w, 0.00943887047f);
    p = fmaf(p, w, 1.00167406f);
    p = fmaf(p, w, 2.83297682f);
  }
  return p * x;
}

// A: per-node gen decision: u(i) < sigmoid(nodes_i . Wp + bp) * anodes_i
__global__ __launch_bounds__(256)
void k_gens(const float* __restrict__ nodes, const float* __restrict__ Wp,
            const float* __restrict__ bp, const float* __restrict__ anodes,
            int* __restrict__ gens, uint32_t kp0, uint32_t kp1) {
  int i = blockIdx.x * 256 + threadIdx.x;
  if (i >= NN) return;
  const float4* row = (const float4*)(nodes + (size_t)i * DD);
  const float4* w = (const float4*)Wp;
  float acc = 0.f;
#pragma unroll
  for (int k = 0; k < DD / 4; ++k) {
    float4 a = row[k], b = w[k];
    acc = fmaf(a.x, b.x, acc); acc = fmaf(a.y, b.y, acc);
    acc = fmaf(a.z, b.z, acc); acc = fmaf(a.w, b.w, acc);
  }
  float prob = 1.0f / (1.0f + expf(-(acc + bp[0])));
  uint32_t b = rbits32(kp0, kp1, (uint32_t)i);
  gens[i] = (u01(b) < prob * anodes[i]) ? 1 : 0;
}

// B: e_active, prefix-scan of gens -> gen_list; naedges via windowed prefix sum
__global__ __launch_bounds__(256)
void k_scan(const float* __restrict__ aedges, const int* __restrict__ gens,
            int* __restrict__ gen_list, float* __restrict__ mask_new,
            float* __restrict__ naedges_out, int* __restrict__ scal) {
  __shared__ int P[EE];        // inclusive prefix count of active edges (32 KB)
  __shared__ int chunk[256];
  __shared__ int s_eact, s_total;
  int tid = threadIdx.x;
  int base = tid * 32;

  // --- load aedges chunk, local count ---
  int av[32]; int aloc = 0;
#pragma unroll
  for (int k = 0; k < 32; ++k) { av[k] = (aedges[base + k] > 0.f) ? 1 : 0; aloc += av[k]; }
  chunk[tid] = aloc; __syncthreads();
  if (tid == 0) {
    int run = 0;
    for (int t = 0; t < 256; ++t) { int v = chunk[t]; chunk[t] = run; run += v; }
    s_eact = run;   // e_active = total active edges
  }
  __syncthreads();
  int e_active = s_eact;
  {
    int run = chunk[tid];
#pragma unroll
    for (int k = 0; k < 32; ++k) { run += av[k]; P[base + k] = run; }
  }

  // --- scan gens -> gen_list, total ---
  int g[32]; int gloc = 0;
#pragma unroll
  for (int k = 0; k < 32; ++k) { g[k] = gens[base + k]; gloc += g[k]; }
  __syncthreads();
  chunk[tid] = gloc; __syncthreads();
  if (tid == 0) {
    int run = 0;
    for (int t = 0; t < 256; ++t) { int v = chunk[t]; chunk[t] = run; run += v; }
    s_total = run;
  }
  __syncthreads();
  int total = s_total;
  {
    int rank = chunk[tid];
#pragma unroll
    for (int k = 0; k < 32; ++k) {
      if (g[k]) {
        if (e_active + rank < EE) gen_list[rank] = base + k;
        rank++;
      }
    }
  }
  if (tid == 0) { scal[0] = e_active; scal[1] = total; }

  int allowed = EE - e_active - 1;
  int n_gens = total;
  if (n_gens > allowed) n_gens = allowed;
  if (n_gens < 0) n_gens = 0;

  __syncthreads();
  // naedges[j] = any aedges in window [j-n_gens, j]  = P[j] - P[j-n_gens-1] > 0
#pragma unroll
  for (int k = 0; k < 32; ++k) {
    int j = base + k;
    int lo = j - n_gens - 1;
    int wsum = P[j] - (lo >= 0 ? P[lo] : 0);
    float dil = (wsum > 0) ? 1.f : 0.f;
    if (j == EE - 1) dil = 0.f;
    naedges_out[j] = dil;
    mask_new[j] = dil * (1.0f - (float)av[k]);
  }
}

// C: categorical(key_samp, scores)[i] for generating rows (rank-strided over gen_list)
__global__ __launch_bounds__(256)
void k_select(const float* __restrict__ nodes, const float* __restrict__ Wq,
              const float* __restrict__ bq, const float* __restrict__ anodes,
              const int* __restrict__ gen_list, const int* __restrict__ scal,
              int* __restrict__ sel, uint32_t ks0, uint32_t ks1) {
  __shared__ float q[DD];
  __shared__ float ni[DD];
  __shared__ float sv[256];
  __shared__ int si[256];
  int tid = threadIdx.x;
  int total = scal[1];
  for (int r = blockIdx.x; r < total; r += gridDim.x) {
    int i = gen_list[r];
    if (tid < DD) ni[tid] = nodes[(size_t)i * DD + tid];
    __syncthreads();
    if (tid < DD) {
      float acc = bq[tid];
      for (int k = 0; k < DD; ++k) acc = fmaf(ni[k], Wq[k * DD + tid], acc);
      q[tid] = acc;
    }
    __syncthreads();

    float bestV = -INFINITY;
    int bestJ = 0;
    for (int j = tid; j < NN; j += 256) {
      const float4* row = (const float4*)(nodes + (size_t)j * DD);
      float acc = 0.f;
#pragma unroll
      for (int k = 0; k < DD / 4; ++k) {
        float4 a = row[k];
        acc = fmaf(a.x, q[4 * k + 0], acc);
        acc = fmaf(a.y, q[4 * k + 1], acc);
        acc = fmaf(a.z, q[4 * k + 2], acc);
        acc = fmaf(a.w, q[4 * k + 3], acc);
      }
      float sc = fminf(fmaxf(acc, -1e4f), 1e4f);
      sc -= (1.0f - anodes[j]) * 1e10f;
      uint32_t b = rbits32(ks0, ks1, (uint32_t)i * NN + (uint32_t)j);
      float u = fmaxf(1.17549435e-38f, u01(b));   // uniform(minval=tiny)
      float gmb = -logf(-logf(u));
      float tot = sc + gmb;
      if (tot > bestV) { bestV = tot; bestJ = j; }
    }
    sv[tid] = bestV; si[tid] = bestJ; __syncthreads();
    for (int off = 128; off > 0; off >>= 1) {
      if (tid < off) {
        float v2 = sv[tid + off]; int j2 = si[tid + off];
        if (v2 > sv[tid] || (v2 == sv[tid] && j2 < si[tid])) { sv[tid] = v2; si[tid] = j2; }
      }
      __syncthreads();
    }
    if (tid == 0) sel[i] = si[0];
    __syncthreads();
  }
}

// D: new_edges = edges + normal(key_edges) * mask_new[:,None]
__global__ __launch_bounds__(256)
void k_edges(const float* __restrict__ edges, const float* __restrict__ mask_new,
             float* __restrict__ out, uint32_t ke0, uint32_t ke1) {
  int t = blockIdx.x * 256 + threadIdx.x;
  int idx = t * 4;
  if (idx >= EE * DD) return;
  int e = idx >> 7;
  float m = mask_new[e];
  float4 v = ((const float4*)edges)[t];
  if (m > 0.f) {
    float* pv = &v.x;
#pragma unroll
    for (int k = 0; k < 4; ++k) {
      uint32_t b = rbits32(ke0, ke1, (uint32_t)(idx + k));
      float u = u01(b);
      float x = fmaf(u, 2.0f, -0.99999994f);  // uniform(nextafter(-1,0), 1)
      x = fmaxf(-0.99999994f, x);
      float nrm = 1.41421354f * erfinv_f32(x);
      pv[k] += nrm * m;
    }
  }
  ((float4*)out)[t] = v;
}

// E: nsend / nrec (float values equal to reference ints)
__global__ __launch_bounds__(256)
void k_sendrec(const int* __restrict__ send, const int* __restrict__ rec,
               const float* __restrict__ mask_new, const int* __restrict__ gen_list,
               const int* __restrict__ sel, const int* __restrict__ scal,
               float* __restrict__ out_nsend, float* __restrict__ out_nrec) {
  int t = blockIdx.x * 256 + threadIdx.x;
  if (t >= EE) return;
  int e_active = scal[0], total = scal[1];
  float m = mask_new[t];
  float sf = (float)send[t] * (1.0f - m);
  float rf = (float)rec[t] * (1.0f - m);
  int r = t - e_active;
  if (r >= 0 && r < total) {
    int i = gen_list[r];
    sf += (float)i;
    rf += (float)sel[i];
  }
  out_nsend[t] = (float)(int)sf;
  out_nrec[t] = (float)(int)rf;
}

extern "C" void kernel_launch(void* const* d_in, const int* in_sizes, int n_in,
                              void* d_out, int out_size, void* d_ws, size_t ws_size,
                              hipStream_t stream) {
  const float* nodes  = (const float*)d_in[0];
  const float* edges  = (const float*)d_in[1];
  const int*   rec    = (const int*)d_in[2];
  const int*   send   = (const int*)d_in[3];
  const float* anodes = (const float*)d_in[4];
  const float* aedges = (const float*)d_in[5];
  const float* Wq     = (const float*)d_in[6];
  const float* bq     = (const float*)d_in[7];
  const float* Wp     = (const float*)d_in[8];
  const float* bp     = (const float*)d_in[9];

  float* out        = (float*)d_out;
  float* out_edges  = out;                    // E*D
  float* out_nsend  = out + (size_t)EE * DD;  // E
  float* out_nrec   = out_nsend + EE;         // E
  float* out_naedge = out_nrec + EE;          // E

  int*   gens     = (int*)d_ws;        // N
  int*   gen_list = gens + NN;         // N
  int*   sel      = gen_list + NN;     // N
  int*   scal     = sel + NN;          // 4
  float* mask_new = (float*)(scal + 4);// E

  uint32_t kp0, kp1, ke0, ke1, ks0, ks1;
  tf2x32(0u, 42u, 0u, 0u, kp0, kp1);
  tf2x32(0u, 42u, 0u, 1u, ke0, ke1);
  tf2x32(0u, 42u, 0u, 2u, ks0, ks1);

  k_gens<<<NN / 256, 256, 0, stream>>>(nodes, Wp, bp, anodes, gens, kp0, kp1);
  k_scan<<<1, 256, 0, stream>>>(aedges, gens, gen_list, mask_new, out_naedge, scal);
  k_select<<<1024, 256, 0, stream>>>(nodes, Wq, bq, anodes, gen_list, scal, sel, ks0, ks1);
  k_edges<<<(EE * DD / 4) / 256, 256, 0, stream>>>(edges, mask_new, out_edges, ke0, ke1);
  k_sendrec<<<EE / 256, 256, 0, stream>>>(send, rec, mask_new, gen_list, sel, scal,
                                          out_nsend, out_nrec);
}

// Round 3
// 86.213 us; speedup vs baseline: 5.5494x; 1.8147x over previous
//
#include <hip/hip_runtime.h>
#include <stdint.h>
#include <math.h>

#define NN 8192
#define EE 8192
#define DD 128

// modern JAX (jax_threefry_partitionable=True):
//   bits(idx) = o0 ^ o1 of threefry(key, (0, idx));
//   split -> subkey j = (o0, o1) of threefry(key, (0, j))
__host__ __device__ inline void tf2x32(uint32_t k0, uint32_t k1, uint32_t c0, uint32_t c1,
                                       uint32_t& o0, uint32_t& o1) {
  uint32_t ks[3] = {k0, k1, 0x1BD11BDAu ^ k0 ^ k1};
  uint32_t x0 = c0 + k0, x1 = c1 + k1;
  const uint32_t rot0[4] = {13u, 15u, 26u, 6u};
  const uint32_t rot1[4] = {17u, 29u, 16u, 24u};
#pragma unroll
  for (int i = 0; i < 5; ++i) {
#pragma unroll
    for (int r = 0; r < 4; ++r) {
      uint32_t d = (i & 1) ? rot1[r] : rot0[r];
      x0 += x1;
      x1 = (x1 << d) | (x1 >> (32u - d));
      x1 ^= x0;
    }
    x0 += ks[(i + 1) % 3];
    x1 += ks[(i + 2) % 3] + (uint32_t)(i + 1);
  }
  o0 = x0; o1 = x1;
}

__device__ inline uint32_t rbits32(uint32_t k0, uint32_t k1, uint32_t idx) {
  uint32_t o0, o1;
  tf2x32(k0, k1, 0u, idx, o0, o1);
  return o0 ^ o1;
}

__device__ inline float u01(uint32_t b) {
  return __uint_as_float((b >> 9) | 0x3f800000u) - 1.0f;
}

// XLA f32 erf_inv polynomial
__device__ inline float erfinv_f32(float x) {
  float w = -log1pf(-x * x);
  float p;
  if (w < 5.0f) {
    w -= 2.5f;
    p = 2.81022636e-08f;
    p = fmaf(p, w, 3.43273939e-07f);
    p = fmaf(p, w, -3.5233877e-06f);
    p = fmaf(p, w, -4.39150654e-06f);
    p = fmaf(p, w, 0.00021858087f);
    p = fmaf(p, w, -0.00125372503f);
    p = fmaf(p, w, -0.00417768164f);
    p = fmaf(p, w, 0.246640727f);
    p = fmaf(p, w, 1.50140941f);
  } else {
    w = sqrtf(w) - 3.0f;
    p = -0.000200214257f;
    p = fmaf(p, w, 0.000100950558f);
    p = fmaf(p, w, 0.00134934322f);
    p = fmaf(p, w, -0.00367342844f);
    p = fmaf(p, w, 0.00573950773f);
    p = fmaf(p, w, -0.0076224613f);
    p = fmaf(p, w, 0.00943887047f);
    p = fmaf(p, w, 1.00167406f);
    p = fmaf(p, w, 2.83297682f);
  }
  return p * x;
}

// A: per-node gen decision
__global__ __launch_bounds__(256)
void k_gens(const float* __restrict__ nodes, const float* __restrict__ Wp,
            const float* __restrict__ bp, const float* __restrict__ anodes,
            int* __restrict__ gens, uint32_t kp0, uint32_t kp1) {
  int i = blockIdx.x * 256 + threadIdx.x;
  if (i >= NN) return;
  const float4* row = (const float4*)(nodes + (size_t)i * DD);
  const float4* w = (const float4*)Wp;
  float acc = 0.f;
#pragma unroll
  for (int k = 0; k < DD / 4; ++k) {
    float4 a = row[k], b = w[k];
    acc = fmaf(a.x, b.x, acc); acc = fmaf(a.y, b.y, acc);
    acc = fmaf(a.z, b.z, acc); acc = fmaf(a.w, b.w, acc);
  }
  float prob = 1.0f / (1.0f + expf(-(acc + bp[0])));
  uint32_t b = rbits32(kp0, kp1, (uint32_t)i);
  gens[i] = (u01(b) < prob * anodes[i]) ? 1 : 0;
}

// B: scans, gen_list, naedges/mask_new, zero the argmax accumulators
__global__ __launch_bounds__(256)
void k_scan(const float* __restrict__ aedges, const int* __restrict__ gens,
            int* __restrict__ gen_list, float* __restrict__ mask_new,
            float* __restrict__ naedges_out, int* __restrict__ scal,
            unsigned long long* __restrict__ packed) {
  __shared__ int P[EE];
  __shared__ int chunk[256];
  __shared__ int s_eact, s_total;
  int tid = threadIdx.x;
  int base = tid * 32;

  int av[32]; int aloc = 0;
#pragma unroll
  for (int k = 0; k < 32; ++k) { av[k] = (aedges[base + k] > 0.f) ? 1 : 0; aloc += av[k]; }
  chunk[tid] = aloc; __syncthreads();
  if (tid == 0) {
    int run = 0;
    for (int t = 0; t < 256; ++t) { int v = chunk[t]; chunk[t] = run; run += v; }
    s_eact = run;
  }
  __syncthreads();
  int e_active = s_eact;
  {
    int run = chunk[tid];
#pragma unroll
    for (int k = 0; k < 32; ++k) { run += av[k]; P[base + k] = run; }
  }

  int g[32]; int gloc = 0;
#pragma unroll
  for (int k = 0; k < 32; ++k) { g[k] = gens[base + k]; gloc += g[k]; }
  __syncthreads();
  chunk[tid] = gloc; __syncthreads();
  if (tid == 0) {
    int run = 0;
    for (int t = 0; t < 256; ++t) { int v = chunk[t]; chunk[t] = run; run += v; }
    s_total = run;
  }
  __syncthreads();
  int total = s_total;
  {
    int rank = chunk[tid];
#pragma unroll
    for (int k = 0; k < 32; ++k) {
      if (g[k]) {
        if (e_active + rank < EE) gen_list[rank] = base + k;
        rank++;
      }
    }
  }
  if (tid == 0) { scal[0] = e_active; scal[1] = total; }

  // zero packed argmax slots for all ranks
  for (int r = tid; r < total; r += 256) packed[r] = 0ull;

  int allowed = EE - e_active - 1;
  int n_gens = total;
  if (n_gens > allowed) n_gens = allowed;
  if (n_gens < 0) n_gens = 0;

  __syncthreads();
#pragma unroll
  for (int k = 0; k < 32; ++k) {
    int j = base + k;
    int lo = j - n_gens - 1;
    int wsum = P[j] - (lo >= 0 ? P[lo] : 0);
    float dil = (wsum > 0) ? 1.f : 0.f;
    if (j == EE - 1) dil = 0.f;
    naedges_out[j] = dil;
    mask_new[j] = dil * (1.0f - (float)av[k]);
  }
}

// C1: queries[r] = nodes[gen_list[r]] @ Wq + bq, for r < total
__global__ __launch_bounds__(128)
void k_queries(const float* __restrict__ nodes, const float* __restrict__ Wq,
               const float* __restrict__ bq, const int* __restrict__ gen_list,
               const int* __restrict__ scal, float* __restrict__ queries) {
  __shared__ float ni[DD];
  int tid = threadIdx.x;
  int total = scal[1];
  for (int r = blockIdx.x; r < total; r += gridDim.x) {
    int i = gen_list[r];
    ni[tid] = nodes[(size_t)i * DD + tid];
    __syncthreads();
    float acc = bq[tid];
    for (int k = 0; k < DD; ++k) acc = fmaf(ni[k], Wq[k * DD + tid], acc);
    queries[(size_t)r * DD + tid] = acc;
    __syncthreads();
  }
}

// C2: chunk-parallel score+gumbel argmax, merged via packed atomicMax.
// key = order-preserving-float(v) << 32 | (NN-1-j)  -> max key == (max v, min j)
__global__ __launch_bounds__(256)
void k_score(const float* __restrict__ nodes, const float* __restrict__ anodes,
             const float* __restrict__ queries, const int* __restrict__ gen_list,
             const int* __restrict__ scal, unsigned long long* __restrict__ packed,
             uint32_t ks0, uint32_t ks1) {
  __shared__ float4 nd[32][32];   // 32 node rows, XOR-swizzled float4 cols
  __shared__ float q[8][DD];
  __shared__ float an[32];
  __shared__ int gi[8];
  int tid = threadIdx.x;
  int j0 = blockIdx.x * 32;
  int total = scal[1];

  // stage 32 node rows: thread t -> row t>>3, 4 float4s
  {
    int jj = tid >> 3, sub = tid & 7;
    const float4* src = (const float4*)(nodes + (size_t)(j0 + jj) * DD);
#pragma unroll
    for (int c = 0; c < 4; ++c) {
      int k4 = sub + 8 * c;
      nd[jj][k4 ^ (jj & 7)] = src[k4];
    }
    if (tid < 32) an[tid] = anodes[j0 + tid];
  }

  int rr = tid >> 5, jj = tid & 31;
  for (int rb = 0; rb < total; rb += 8) {
    __syncthreads();
    // load 8 query rows (one float4 per thread) + gen ids
    {
      int lr = rb + (tid >> 5);
      int k4 = tid & 31;
      if (lr < total) {
        ((float4*)q[tid >> 5])[k4] = ((const float4*)(queries + (size_t)lr * DD))[k4];
        if (k4 == 0) gi[tid >> 5] = gen_list[lr];
      }
    }
    __syncthreads();

    int r = rb + rr;
    if (r < total) {
      const float4* qv = (const float4*)q[rr];
      float acc = 0.f;
#pragma unroll
      for (int k4 = 0; k4 < 32; ++k4) {
        float4 n = nd[jj][k4 ^ (jj & 7)];
        float4 qq = qv[k4];
        acc = fmaf(n.x, qq.x, acc); acc = fmaf(n.y, qq.y, acc);
        acc = fmaf(n.z, qq.z, acc); acc = fmaf(n.w, qq.w, acc);
      }
      int j = j0 + jj;
      float sc = fminf(fmaxf(acc, -1e4f), 1e4f);
      sc -= (1.0f - an[jj]) * 1e10f;
      uint32_t bidx = (uint32_t)gi[rr] * NN + (uint32_t)j;
      uint32_t b = rbits32(ks0, ks1, bidx);
      float u = fmaxf(1.17549435e-38f, u01(b));
      float gmb = -logf(-logf(u));
      float v = sc + gmb;
      int jbest = j;
      // width-32 argmax, tie -> lowest j
#pragma unroll
      for (int m = 16; m; m >>= 1) {
        float ov = __shfl_xor(v, m, 32);
        int oj = __shfl_xor(jbest, m, 32);
        if (ov > v || (ov == v && oj < jbest)) { v = ov; jbest = oj; }
      }
      if (jj == 0) {
        uint32_t fb = __float_as_uint(v);
        fb = (fb & 0x80000000u) ? ~fb : (fb | 0x80000000u);
        unsigned long long key =
            ((unsigned long long)fb << 32) | (uint32_t)(NN - 1 - jbest);
        atomicMax(&packed[r], key);
      }
    }
  }
}

// D: new_edges = edges + normal(key_edges) * mask_new[:,None]
__global__ __launch_bounds__(256)
void k_edges(const float* __restrict__ edges, const float* __restrict__ mask_new,
             float* __restrict__ out, uint32_t ke0, uint32_t ke1) {
  int t = blockIdx.x * 256 + threadIdx.x;
  int idx = t * 4;
  if (idx >= EE * DD) return;
  int e = idx >> 7;
  float m = mask_new[e];
  float4 v = ((const float4*)edges)[t];
  if (m > 0.f) {
    float* pv = &v.x;
#pragma unroll
    for (int k = 0; k < 4; ++k) {
      uint32_t b = rbits32(ke0, ke1, (uint32_t)(idx + k));
      float u = u01(b);
      float x = fmaf(u, 2.0f, -0.99999994f);
      x = fmaxf(-0.99999994f, x);
      float nrm = 1.41421354f * erfinv_f32(x);
      pv[k] += nrm * m;
    }
  }
  ((float4*)out)[t] = v;
}

// E: nsend / nrec
__global__ __launch_bounds__(256)
void k_sendrec(const int* __restrict__ send, const int* __restrict__ rec,
               const float* __restrict__ mask_new, const int* __restrict__ gen_list,
               const unsigned long long* __restrict__ packed,
               const int* __restrict__ scal,
               float* __restrict__ out_nsend, float* __restrict__ out_nrec) {
  int t = blockIdx.x * 256 + threadIdx.x;
  if (t >= EE) return;
  int e_active = scal[0], total = scal[1];
  float m = mask_new[t];
  float sf = (float)send[t] * (1.0f - m);
  float rf = (float)rec[t] * (1.0f - m);
  int r = t - e_active;
  if (r >= 0 && r < total) {
    int i = gen_list[r];
    int jsel = (NN - 1) - (int)(packed[r] & 0xFFFFFFFFull);
    sf += (float)i;
    rf += (float)jsel;
  }
  out_nsend[t] = (float)(int)sf;
  out_nrec[t] = (float)(int)rf;
}

extern "C" void kernel_launch(void* const* d_in, const int* in_sizes, int n_in,
                              void* d_out, int out_size, void* d_ws, size_t ws_size,
                              hipStream_t stream) {
  const float* nodes  = (const float*)d_in[0];
  const float* edges  = (const float*)d_in[1];
  const int*   rec    = (const int*)d_in[2];
  const int*   send   = (const int*)d_in[3];
  const float* anodes = (const float*)d_in[4];
  const float* aedges = (const float*)d_in[5];
  const float* Wq     = (const float*)d_in[6];
  const float* bq     = (const float*)d_in[7];
  const float* Wp     = (const float*)d_in[8];
  const float* bp     = (const float*)d_in[9];

  float* out        = (float*)d_out;
  float* out_edges  = out;                    // E*D
  float* out_nsend  = out + (size_t)EE * DD;  // E
  float* out_nrec   = out_nsend + EE;         // E
  float* out_naedge = out_nrec + EE;          // E

  char* w = (char*)d_ws;
  int*   gens     = (int*)w;                         // 32KB
  int*   gen_list = (int*)(w + 32768);               // 32KB
  int*   scal     = (int*)(w + 65536);               // 64B
  float* mask_new = (float*)(w + 65600);             // 32KB
  unsigned long long* packed = (unsigned long long*)(w + 98368); // 64KB
  float* queries  = (float*)(w + 163904);            // total*DD*4

  uint32_t kp0, kp1, ke0, ke1, ks0, ks1;
  tf2x32(0u, 42u, 0u, 0u, kp0, kp1);
  tf2x32(0u, 42u, 0u, 1u, ke0, ke1);
  tf2x32(0u, 42u, 0u, 2u, ks0, ks1);

  k_gens<<<NN / 256, 256, 0, stream>>>(nodes, Wp, bp, anodes, gens, kp0, kp1);
  k_scan<<<1, 256, 0, stream>>>(aedges, gens, gen_list, mask_new, out_naedge, scal, packed);
  k_queries<<<128, 128, 0, stream>>>(nodes, Wq, bq, gen_list, scal, queries);
  k_score<<<NN / 32, 256, 0, stream>>>(nodes, anodes, queries, gen_list, scal, packed, ks0, ks1);
  k_edges<<<(EE * DD / 4) / 256, 256, 0, stream>>>(edges, mask_new, out_edges, ke0, ke1);
  k_sendrec<<<EE / 256, 256, 0, stream>>>(send, rec, mask_new, gen_list, packed, scal,
                                          out_nsend, out_nrec);
}

// Round 4
// 78.890 us; speedup vs baseline: 6.0645x; 1.0928x over previous
//
#include <hip/hip_runtime.h>
#include <stdint.h>
#include <math.h>

#define NN 8192
#define EE 8192
#define DD 128

// modern JAX (jax_threefry_partitionable=True):
//   bits(idx) = o0 ^ o1 of threefry(key, (0, idx));
//   split -> subkey j = (o0, o1) of threefry(key, (0, j))
__host__ __device__ inline void tf2x32(uint32_t k0, uint32_t k1, uint32_t c0, uint32_t c1,
                                       uint32_t& o0, uint32_t& o1) {
  uint32_t ks[3] = {k0, k1, 0x1BD11BDAu ^ k0 ^ k1};
  uint32_t x0 = c0 + k0, x1 = c1 + k1;
  const uint32_t rot0[4] = {13u, 15u, 26u, 6u};
  const uint32_t rot1[4] = {17u, 29u, 16u, 24u};
#pragma unroll
  for (int i = 0; i < 5; ++i) {
#pragma unroll
    for (int r = 0; r < 4; ++r) {
      uint32_t d = (i & 1) ? rot1[r] : rot0[r];
      x0 += x1;
      x1 = (x1 << d) | (x1 >> (32u - d));
      x1 ^= x0;
    }
    x0 += ks[(i + 1) % 3];
    x1 += ks[(i + 2) % 3] + (uint32_t)(i + 1);
  }
  o0 = x0; o1 = x1;
}

__device__ inline uint32_t rbits32(uint32_t k0, uint32_t k1, uint32_t idx) {
  uint32_t o0, o1;
  tf2x32(k0, k1, 0u, idx, o0, o1);
  return o0 ^ o1;
}

__device__ inline float u01(uint32_t b) {
  return __uint_as_float((b >> 9) | 0x3f800000u) - 1.0f;
}

// XLA f32 erf_inv polynomial
__device__ inline float erfinv_f32(float x) {
  float w = -log1pf(-x * x);
  float p;
  if (w < 5.0f) {
    w -= 2.5f;
    p = 2.81022636e-08f;
    p = fmaf(p, w, 3.43273939e-07f);
    p = fmaf(p, w, -3.5233877e-06f);
    p = fmaf(p, w, -4.39150654e-06f);
    p = fmaf(p, w, 0.00021858087f);
    p = fmaf(p, w, -0.00125372503f);
    p = fmaf(p, w, -0.00417768164f);
    p = fmaf(p, w, 0.246640727f);
    p = fmaf(p, w, 1.50140941f);
  } else {
    w = sqrtf(w) - 3.0f;
    p = -0.000200214257f;
    p = fmaf(p, w, 0.000100950558f);
    p = fmaf(p, w, 0.00134934322f);
    p = fmaf(p, w, -0.00367342844f);
    p = fmaf(p, w, 0.00573950773f);
    p = fmaf(p, w, -0.0076224613f);
    p = fmaf(p, w, 0.00943887047f);
    p = fmaf(p, w, 1.00167406f);
    p = fmaf(p, w, 2.83297682f);
  }
  return p * x;
}

// A: per-node gen decision
__global__ __launch_bounds__(256)
void k_gens(const float* __restrict__ nodes, const float* __restrict__ Wp,
            const float* __restrict__ bp, const float* __restrict__ anodes,
            int* __restrict__ gens, uint32_t kp0, uint32_t kp1) {
  int i = blockIdx.x * 256 + threadIdx.x;
  if (i >= NN) return;
  const float4* row = (const float4*)(nodes + (size_t)i * DD);
  const float4* w = (const float4*)Wp;
  float acc = 0.f;
#pragma unroll
  for (int k = 0; k < DD / 4; ++k) {
    float4 a = row[k], b = w[k];
    acc = fmaf(a.x, b.x, acc); acc = fmaf(a.y, b.y, acc);
    acc = fmaf(a.z, b.z, acc); acc = fmaf(a.w, b.w, acc);
  }
  float prob = 1.0f / (1.0f + expf(-(acc + bp[0])));
  uint32_t b = rbits32(kp0, kp1, (uint32_t)i);
  gens[i] = (u01(b) < prob * anodes[i]) ? 1 : 0;
}

// B: scans, gen_list, naedges/mask_new, zero the argmax accumulators
__global__ __launch_bounds__(256)
void k_scan(const float* __restrict__ aedges, const int* __restrict__ gens,
            int* __restrict__ gen_list, float* __restrict__ mask_new,
            float* __restrict__ naedges_out, int* __restrict__ scal,
            unsigned long long* __restrict__ packed) {
  __shared__ int P[EE];
  __shared__ int chunk[256];
  __shared__ int s_eact, s_total;
  int tid = threadIdx.x;
  int base = tid * 32;

  int av[32]; int aloc = 0;
#pragma unroll
  for (int k = 0; k < 32; ++k) { av[k] = (aedges[base + k] > 0.f) ? 1 : 0; aloc += av[k]; }
  chunk[tid] = aloc; __syncthreads();
  if (tid == 0) {
    int run = 0;
    for (int t = 0; t < 256; ++t) { int v = chunk[t]; chunk[t] = run; run += v; }
    s_eact = run;
  }
  __syncthreads();
  int e_active = s_eact;
  {
    int run = chunk[tid];
#pragma unroll
    for (int k = 0; k < 32; ++k) { run += av[k]; P[base + k] = run; }
  }

  int g[32]; int gloc = 0;
#pragma unroll
  for (int k = 0; k < 32; ++k) { g[k] = gens[base + k]; gloc += g[k]; }
  __syncthreads();
  chunk[tid] = gloc; __syncthreads();
  if (tid == 0) {
    int run = 0;
    for (int t = 0; t < 256; ++t) { int v = chunk[t]; chunk[t] = run; run += v; }
    s_total = run;
  }
  __syncthreads();
  int total = s_total;
  {
    int rank = chunk[tid];
#pragma unroll
    for (int k = 0; k < 32; ++k) {
      if (g[k]) {
        if (e_active + rank < EE) gen_list[rank] = base + k;
        rank++;
      }
    }
  }
  if (tid == 0) { scal[0] = e_active; scal[1] = total; }

  // zero packed argmax slots for all ranks
  for (int r = tid; r < total; r += 256) packed[r] = 0ull;

  int allowed = EE - e_active - 1;
  int n_gens = total;
  if (n_gens > allowed) n_gens = allowed;
  if (n_gens < 0) n_gens = 0;

  __syncthreads();
#pragma unroll
  for (int k = 0; k < 32; ++k) {
    int j = base + k;
    int lo = j - n_gens - 1;
    int wsum = P[j] - (lo >= 0 ? P[lo] : 0);
    float dil = (wsum > 0) ? 1.f : 0.f;
    if (j == EE - 1) dil = 0.f;
    naedges_out[j] = dil;
    mask_new[j] = dil * (1.0f - (float)av[k]);
  }
}

// C1: queries[r] = nodes[gen_list[r]] @ Wq + bq, for r < total
__global__ __launch_bounds__(128)
void k_queries(const float* __restrict__ nodes, const float* __restrict__ Wq,
               const float* __restrict__ bq, const int* __restrict__ gen_list,
               const int* __restrict__ scal, float* __restrict__ queries) {
  __shared__ float ni[DD];
  int tid = threadIdx.x;
  int total = scal[1];
  for (int r = blockIdx.x; r < total; r += gridDim.x) {
    int i = gen_list[r];
    ni[tid] = nodes[(size_t)i * DD + tid];
    __syncthreads();
    float acc = bq[tid];
    for (int k = 0; k < DD; ++k) acc = fmaf(ni[k], Wq[k * DD + tid], acc);
    queries[(size_t)r * DD + tid] = acc;
    __syncthreads();
  }
}

// C2: (node-chunk x rank-tile) parallel score+gumbel argmax, packed atomicMax merge.
// key = order-preserving-float(v) << 32 | (NN-1-j)  -> max key == (max v, min j)
__global__ __launch_bounds__(256)
void k_score(const float* __restrict__ nodes, const float* __restrict__ anodes,
             const float* __restrict__ queries, const int* __restrict__ gen_list,
             const int* __restrict__ scal, unsigned long long* __restrict__ packed,
             uint32_t ks0, uint32_t ks1) {
  __shared__ float4 nd[32][32];   // 32 node rows, XOR-swizzled float4 cols
  __shared__ float q[8][DD];
  __shared__ float an[32];
  __shared__ int gi[8];
  int tid = threadIdx.x;
  int j0 = blockIdx.x * 32;
  int total = scal[1];
  int rt0 = blockIdx.y * 8;
  if (rt0 >= total) return;     // dead rank tile: exit before staging

  // stage 32 node rows: thread t -> row t>>3, 4 float4s (once per block)
  {
    int jj = tid >> 3, sub = tid & 7;
    const float4* src = (const float4*)(nodes + (size_t)(j0 + jj) * DD);
#pragma unroll
    for (int c = 0; c < 4; ++c) {
      int k4 = sub + 8 * c;
      nd[jj][k4 ^ (jj & 7)] = src[k4];
    }
    if (tid < 32) an[tid] = anodes[j0 + tid];
  }

  int rr = tid >> 5, jj = tid & 31;
  // grid-stride over rank tiles (1 iteration unless total > 8*gridDim.y = 128)
  for (int rb = rt0; rb < total; rb += 8 * gridDim.y) {
    __syncthreads();
    {
      int lr = rb + (tid >> 5);
      int k4 = tid & 31;
      if (lr < total) {
        ((float4*)q[tid >> 5])[k4] = ((const float4*)(queries + (size_t)lr * DD))[k4];
        if (k4 == 0) gi[tid >> 5] = gen_list[lr];
      }
    }
    __syncthreads();

    int r = rb + rr;
    if (r < total) {
      const float4* qv = (const float4*)q[rr];
      float acc = 0.f;
#pragma unroll
      for (int k4 = 0; k4 < 32; ++k4) {
        float4 n = nd[jj][k4 ^ (jj & 7)];
        float4 qq = qv[k4];
        acc = fmaf(n.x, qq.x, acc); acc = fmaf(n.y, qq.y, acc);
        acc = fmaf(n.z, qq.z, acc); acc = fmaf(n.w, qq.w, acc);
      }
      int j = j0 + jj;
      float sc = fminf(fmaxf(acc, -1e4f), 1e4f);
      sc -= (1.0f - an[jj]) * 1e10f;
      uint32_t bidx = (uint32_t)gi[rr] * NN + (uint32_t)j;
      uint32_t b = rbits32(ks0, ks1, bidx);
      float u = fmaxf(1.17549435e-38f, u01(b));
      float gmb = -logf(-logf(u));
      float v = sc + gmb;
      int jbest = j;
#pragma unroll
      for (int m = 16; m; m >>= 1) {
        float ov = __shfl_xor(v, m, 32);
        int oj = __shfl_xor(jbest, m, 32);
        if (ov > v || (ov == v && oj < jbest)) { v = ov; jbest = oj; }
      }
      if (jj == 0) {
        uint32_t fb = __float_as_uint(v);
        fb = (fb & 0x80000000u) ? ~fb : (fb | 0x80000000u);
        unsigned long long key =
            ((unsigned long long)fb << 32) | (uint32_t)(NN - 1 - jbest);
        atomicMax(&packed[r], key);
      }
    }
  }
}

// D: new_edges = edges + normal(key_edges) * mask_new[:,None]
__global__ __launch_bounds__(256)
void k_edges(const float* __restrict__ edges, const float* __restrict__ mask_new,
             float* __restrict__ out, uint32_t ke0, uint32_t ke1) {
  int t = blockIdx.x * 256 + threadIdx.x;
  int idx = t * 4;
  if (idx >= EE * DD) return;
  int e = idx >> 7;
  float m = mask_new[e];
  float4 v = ((const float4*)edges)[t];
  if (m > 0.f) {
    float* pv = &v.x;
#pragma unroll
    for (int k = 0; k < 4; ++k) {
      uint32_t b = rbits32(ke0, ke1, (uint32_t)(idx + k));
      float u = u01(b);
      float x = fmaf(u, 2.0f, -0.99999994f);
      x = fmaxf(-0.99999994f, x);
      float nrm = 1.41421354f * erfinv_f32(x);
      pv[k] += nrm * m;
    }
  }
  ((float4*)out)[t] = v;
}

// E: nsend / nrec
__global__ __launch_bounds__(256)
void k_sendrec(const int* __restrict__ send, const int* __restrict__ rec,
               const float* __restrict__ mask_new, const int* __restrict__ gen_list,
               const unsigned long long* __restrict__ packed,
               const int* __restrict__ scal,
               float* __restrict__ out_nsend, float* __restrict__ out_nrec) {
  int t = blockIdx.x * 256 + threadIdx.x;
  if (t >= EE) return;
  int e_active = scal[0], total = scal[1];
  float m = mask_new[t];
  float sf = (float)send[t] * (1.0f - m);
  float rf = (float)rec[t] * (1.0f - m);
  int r = t - e_active;
  if (r >= 0 && r < total) {
    int i = gen_list[r];
    int jsel = (NN - 1) - (int)(packed[r] & 0xFFFFFFFFull);
    sf += (float)i;
    rf += (float)jsel;
  }
  out_nsend[t] = (float)(int)sf;
  out_nrec[t] = (float)(int)rf;
}

extern "C" void kernel_launch(void* const* d_in, const int* in_sizes, int n_in,
                              void* d_out, int out_size, void* d_ws, size_t ws_size,
                              hipStream_t stream) {
  const float* nodes  = (const float*)d_in[0];
  const float* edges  = (const float*)d_in[1];
  const int*   rec    = (const int*)d_in[2];
  const int*   send   = (const int*)d_in[3];
  const float* anodes = (const float*)d_in[4];
  const float* aedges = (const float*)d_in[5];
  const float* Wq     = (const float*)d_in[6];
  const float* bq     = (const float*)d_in[7];
  const float* Wp     = (const float*)d_in[8];
  const float* bp     = (const float*)d_in[9];

  float* out        = (float*)d_out;
  float* out_edges  = out;                    // E*D
  float* out_nsend  = out + (size_t)EE * DD;  // E
  float* out_nrec   = out_nsend + EE;         // E
  float* out_naedge = out_nrec + EE;          // E

  char* w = (char*)d_ws;
  int*   gens     = (int*)w;                         // 32KB
  int*   gen_list = (int*)(w + 32768);               // 32KB
  int*   scal     = (int*)(w + 65536);               // 64B
  float* mask_new = (float*)(w + 65600);             // 32KB
  unsigned long long* packed = (unsigned long long*)(w + 98368); // 64KB
  float* queries  = (float*)(w + 163904);            // total*DD*4

  uint32_t kp0, kp1, ke0, ke1, ks0, ks1;
  tf2x32(0u, 42u, 0u, 0u, kp0, kp1);
  tf2x32(0u, 42u, 0u, 1u, ke0, ke1);
  tf2x32(0u, 42u, 0u, 2u, ks0, ks1);

  k_gens<<<NN / 256, 256, 0, stream>>>(nodes, Wp, bp, anodes, gens, kp0, kp1);
  k_scan<<<1, 256, 0, stream>>>(aedges, gens, gen_list, mask_new, out_naedge, scal, packed);
  k_queries<<<128, 128, 0, stream>>>(nodes, Wq, bq, gen_list, scal, queries);
  k_score<<<dim3(NN / 32, 16), 256, 0, stream>>>(nodes, anodes, queries, gen_list, scal,
                                                 packed, ks0, ks1);
  k_edges<<<(EE * DD / 4) / 256, 256, 0, stream>>>(edges, mask_new, out_edges, ke0, ke1);
  k_sendrec<<<EE / 256, 256, 0, stream>>>(send, rec, mask_new, gen_list, packed, scal,
                                          out_nsend, out_nrec);
}

// Round 5
// 51.933 us; speedup vs baseline: 9.2125x; 1.5191x over previous
//
#include <hip/hip_runtime.h>
#include <stdint.h>
#include <math.h>

#define NN 8192
#define EE 8192
#define DD 128

// modern JAX (jax_threefry_partitionable=True):
//   bits(idx) = o0 ^ o1 of threefry(key, (0, idx));
//   split -> subkey j = (o0, o1) of threefry(key, (0, j))
__host__ __device__ inline void tf2x32(uint32_t k0, uint32_t k1, uint32_t c0, uint32_t c1,
                                       uint32_t& o0, uint32_t& o1) {
  uint32_t ks[3] = {k0, k1, 0x1BD11BDAu ^ k0 ^ k1};
  uint32_t x0 = c0 + k0, x1 = c1 + k1;
  const uint32_t rot0[4] = {13u, 15u, 26u, 6u};
  const uint32_t rot1[4] = {17u, 29u, 16u, 24u};
#pragma unroll
  for (int i = 0; i < 5; ++i) {
#pragma unroll
    for (int r = 0; r < 4; ++r) {
      uint32_t d = (i & 1) ? rot1[r] : rot0[r];
      x0 += x1;
      x1 = (x1 << d) | (x1 >> (32u - d));
      x1 ^= x0;
    }
    x0 += ks[(i + 1) % 3];
    x1 += ks[(i + 2) % 3] + (uint32_t)(i + 1);
  }
  o0 = x0; o1 = x1;
}

__device__ inline uint32_t rbits32(uint32_t k0, uint32_t k1, uint32_t idx) {
  uint32_t o0, o1;
  tf2x32(k0, k1, 0u, idx, o0, o1);
  return o0 ^ o1;
}

__device__ inline float u01(uint32_t b) {
  return __uint_as_float((b >> 9) | 0x3f800000u) - 1.0f;
}

// XLA f32 erf_inv polynomial
__device__ inline float erfinv_f32(float x) {
  float w = -log1pf(-x * x);
  float p;
  if (w < 5.0f) {
    w -= 2.5f;
    p = 2.81022636e-08f;
    p = fmaf(p, w, 3.43273939e-07f);
    p = fmaf(p, w, -3.5233877e-06f);
    p = fmaf(p, w, -4.39150654e-06f);
    p = fmaf(p, w, 0.00021858087f);
    p = fmaf(p, w, -0.00125372503f);
    p = fmaf(p, w, -0.00417768164f);
    p = fmaf(p, w, 0.246640727f);
    p = fmaf(p, w, 1.50140941f);
  } else {
    w = sqrtf(w) - 3.0f;
    p = -0.000200214257f;
    p = fmaf(p, w, 0.000100950558f);
    p = fmaf(p, w, 0.00134934322f);
    p = fmaf(p, w, -0.00367342844f);
    p = fmaf(p, w, 0.00573950773f);
    p = fmaf(p, w, -0.0076224613f);
    p = fmaf(p, w, 0.00943887047f);
    p = fmaf(p, w, 1.00167406f);
    p = fmaf(p, w, 2.83297682f);
  }
  return p * x;
}

// A: per-node gen decision
__global__ __launch_bounds__(256)
void k_gens(const float* __restrict__ nodes, const float* __restrict__ Wp,
            const float* __restrict__ bp, const float* __restrict__ anodes,
            int* __restrict__ gens, uint32_t kp0, uint32_t kp1) {
  int i = blockIdx.x * 256 + threadIdx.x;
  if (i >= NN) return;
  const float4* row = (const float4*)(nodes + (size_t)i * DD);
  const float4* w = (const float4*)Wp;
  float acc = 0.f;
#pragma unroll
  for (int k = 0; k < DD / 4; ++k) {
    float4 a = row[k], b = w[k];
    acc = fmaf(a.x, b.x, acc); acc = fmaf(a.y, b.y, acc);
    acc = fmaf(a.z, b.z, acc); acc = fmaf(a.w, b.w, acc);
  }
  float prob = 1.0f / (1.0f + expf(-(acc + bp[0])));
  uint32_t b = rbits32(kp0, kp1, (uint32_t)i);
  gens[i] = (u01(b) < prob * anodes[i]) ? 1 : 0;
}

// B: scans, gen_list, naedges/mask_new, zero merge accumulators
__global__ __launch_bounds__(256)
void k_scan(const float* __restrict__ aedges, const int* __restrict__ gens,
            int* __restrict__ gen_list, float* __restrict__ mask_new,
            float* __restrict__ naedges_out, int* __restrict__ scal,
            unsigned long long* __restrict__ packed,
            unsigned long long* __restrict__ partial) {
  __shared__ int P[EE];
  __shared__ int chunk[256];
  __shared__ int s_eact, s_total;
  int tid = threadIdx.x;
  int base = tid * 32;

  int av[32]; int aloc = 0;
#pragma unroll
  for (int k = 0; k < 32; ++k) { av[k] = (aedges[base + k] > 0.f) ? 1 : 0; aloc += av[k]; }
  chunk[tid] = aloc; __syncthreads();
  if (tid == 0) {
    int run = 0;
    for (int t = 0; t < 256; ++t) { int v = chunk[t]; chunk[t] = run; run += v; }
    s_eact = run;
  }
  __syncthreads();
  int e_active = s_eact;
  {
    int run = chunk[tid];
#pragma unroll
    for (int k = 0; k < 32; ++k) { run += av[k]; P[base + k] = run; }
  }

  int g[32]; int gloc = 0;
#pragma unroll
  for (int k = 0; k < 32; ++k) { g[k] = gens[base + k]; gloc += g[k]; }
  __syncthreads();
  chunk[tid] = gloc; __syncthreads();
  if (tid == 0) {
    int run = 0;
    for (int t = 0; t < 256; ++t) { int v = chunk[t]; chunk[t] = run; run += v; }
    s_total = run;
  }
  __syncthreads();
  int total = s_total;
  {
    int rank = chunk[tid];
#pragma unroll
    for (int k = 0; k < 32; ++k) {
      if (g[k]) {
        if (e_active + rank < EE) gen_list[rank] = base + k;
        rank++;
      }
    }
  }
  if (tid == 0) { scal[0] = e_active; scal[1] = total; }

  // zero merge accumulators
  for (int r = tid; r < total; r += 256) packed[r] = 0ull;
  int npart = (total < 256 ? total : 256) * 32;
  for (int idx = tid; idx < npart; idx += 256) partial[idx] = 0ull;

  int allowed = EE - e_active - 1;
  int n_gens = total;
  if (n_gens > allowed) n_gens = allowed;
  if (n_gens < 0) n_gens = 0;

  __syncthreads();
#pragma unroll
  for (int k = 0; k < 32; ++k) {
    int j = base + k;
    int lo = j - n_gens - 1;
    int wsum = P[j] - (lo >= 0 ? P[lo] : 0);
    float dil = (wsum > 0) ? 1.f : 0.f;
    if (j == EE - 1) dil = 0.f;
    naedges_out[j] = dil;
    mask_new[j] = dil * (1.0f - (float)av[k]);
  }
}

// C1: queries[r] = nodes[gen_list[r]] @ Wq + bq, for r < total
__global__ __launch_bounds__(128)
void k_queries(const float* __restrict__ nodes, const float* __restrict__ Wq,
               const float* __restrict__ bq, const int* __restrict__ gen_list,
               const int* __restrict__ scal, float* __restrict__ queries) {
  __shared__ float ni[DD];
  int tid = threadIdx.x;
  int total = scal[1];
  for (int r = blockIdx.x; r < total; r += gridDim.x) {
    int i = gen_list[r];
    ni[tid] = nodes[(size_t)i * DD + tid];
    __syncthreads();
    float acc = bq[tid];
    for (int k = 0; k < DD; ++k) acc = fmaf(ni[k], Wq[k * DD + tid], acc);
    queries[(size_t)r * DD + tid] = acc;
    __syncthreads();
  }
}

// C2: (node-chunk x rank-tile) score+gumbel argmax; hierarchical merge:
// block winner -> partial[r][x>>3] (8-way atomic contention, 1920 slots)
// key = order-preserving-float(v) << 32 | (NN-1-j)  -> max key == (max v, min j)
__global__ __launch_bounds__(256)
void k_score(const float* __restrict__ nodes, const float* __restrict__ anodes,
             const float* __restrict__ queries, const int* __restrict__ gen_list,
             const int* __restrict__ scal, unsigned long long* __restrict__ packed,
             unsigned long long* __restrict__ partial,
             uint32_t ks0, uint32_t ks1) {
  __shared__ float4 nd[32][32];   // 32 node rows, XOR-swizzled float4 cols
  __shared__ float q[8][DD];
  __shared__ float an[32];
  __shared__ int gi[8];
  int tid = threadIdx.x;
  int j0 = blockIdx.x * 32;
  int total = scal[1];
  int rt0 = blockIdx.y * 8;
  if (rt0 >= total) return;     // dead rank tile: exit before staging

  {
    int jj = tid >> 3, sub = tid & 7;
    const float4* src = (const float4*)(nodes + (size_t)(j0 + jj) * DD);
#pragma unroll
    for (int c = 0; c < 4; ++c) {
      int k4 = sub + 8 * c;
      nd[jj][k4 ^ (jj & 7)] = src[k4];
    }
    if (tid < 32) an[tid] = anodes[j0 + tid];
  }

  int rr = tid >> 5, jj = tid & 31;
  for (int rb = rt0; rb < total; rb += 8 * gridDim.y) {
    __syncthreads();
    {
      int lr = rb + (tid >> 5);
      int k4 = tid & 31;
      if (lr < total) {
        ((float4*)q[tid >> 5])[k4] = ((const float4*)(queries + (size_t)lr * DD))[k4];
        if (k4 == 0) gi[tid >> 5] = gen_list[lr];
      }
    }
    __syncthreads();

    int r = rb + rr;
    if (r < total) {
      const float4* qv = (const float4*)q[rr];
      float acc = 0.f;
#pragma unroll
      for (int k4 = 0; k4 < 32; ++k4) {
        float4 n = nd[jj][k4 ^ (jj & 7)];
        float4 qq = qv[k4];
        acc = fmaf(n.x, qq.x, acc); acc = fmaf(n.y, qq.y, acc);
        acc = fmaf(n.z, qq.z, acc); acc = fmaf(n.w, qq.w, acc);
      }
      int j = j0 + jj;
      float sc = fminf(fmaxf(acc, -1e4f), 1e4f);
      sc -= (1.0f - an[jj]) * 1e10f;
      uint32_t bidx = (uint32_t)gi[rr] * NN + (uint32_t)j;
      uint32_t b = rbits32(ks0, ks1, bidx);
      float u = fmaxf(1.17549435e-38f, u01(b));
      float gmb = -logf(-logf(u));
      float v = sc + gmb;
      int jbest = j;
#pragma unroll
      for (int m = 16; m; m >>= 1) {
        float ov = __shfl_xor(v, m, 32);
        int oj = __shfl_xor(jbest, m, 32);
        if (ov > v || (ov == v && oj < jbest)) { v = ov; jbest = oj; }
      }
      if (jj == 0) {
        uint32_t fb = __float_as_uint(v);
        fb = (fb & 0x80000000u) ? ~fb : (fb | 0x80000000u);
        unsigned long long key =
            ((unsigned long long)fb << 32) | (uint32_t)(NN - 1 - jbest);
        if (r < 256) atomicMax(&partial[r * 32 + (blockIdx.x >> 3)], key);
        else         atomicMax(&packed[r], key);
      }
    }
  }
}

// C3: reduce 32 partials per rank -> packed[r]
__global__ __launch_bounds__(64)
void k_reduce(const unsigned long long* __restrict__ partial,
              const int* __restrict__ scal,
              unsigned long long* __restrict__ packed) {
  int r = blockIdx.x;
  int total = scal[1];
  if (r >= total || r >= 256) return;
  int lane = threadIdx.x;
  unsigned long long v = (lane < 32) ? partial[r * 32 + lane] : 0ull;
#pragma unroll
  for (int m = 32; m; m >>= 1) {
    unsigned long long o = __shfl_xor(v, m, 64);
    if (o > v) v = o;
  }
  if (lane == 0) packed[r] = v;
}

// D: new_edges = edges + normal(key_edges) * mask_new[:,None]
__global__ __launch_bounds__(256)
void k_edges(const float* __restrict__ edges, const float* __restrict__ mask_new,
             float* __restrict__ out, uint32_t ke0, uint32_t ke1) {
  int t = blockIdx.x * 256 + threadIdx.x;
  int idx = t * 4;
  if (idx >= EE * DD) return;
  int e = idx >> 7;
  float m = mask_new[e];
  float4 v = ((const float4*)edges)[t];
  if (m > 0.f) {
    float* pv = &v.x;
#pragma unroll
    for (int k = 0; k < 4; ++k) {
      uint32_t b = rbits32(ke0, ke1, (uint32_t)(idx + k));
      float u = u01(b);
      float x = fmaf(u, 2.0f, -0.99999994f);
      x = fmaxf(-0.99999994f, x);
      float nrm = 1.41421354f * erfinv_f32(x);
      pv[k] += nrm * m;
    }
  }
  ((float4*)out)[t] = v;
}

// E: nsend / nrec
__global__ __launch_bounds__(256)
void k_sendrec(const int* __restrict__ send, const int* __restrict__ rec,
               const float* __restrict__ mask_new, const int* __restrict__ gen_list,
               const unsigned long long* __restrict__ packed,
               const int* __restrict__ scal,
               float* __restrict__ out_nsend, float* __restrict__ out_nrec) {
  int t = blockIdx.x * 256 + threadIdx.x;
  if (t >= EE) return;
  int e_active = scal[0], total = scal[1];
  float m = mask_new[t];
  float sf = (float)send[t] * (1.0f - m);
  float rf = (float)rec[t] * (1.0f - m);
  int r = t - e_active;
  if (r >= 0 && r < total) {
    int i = gen_list[r];
    int jsel = (NN - 1) - (int)(packed[r] & 0xFFFFFFFFull);
    sf += (float)i;
    rf += (float)jsel;
  }
  out_nsend[t] = (float)(int)sf;
  out_nrec[t] = (float)(int)rf;
}

extern "C" void kernel_launch(void* const* d_in, const int* in_sizes, int n_in,
                              void* d_out, int out_size, void* d_ws, size_t ws_size,
                              hipStream_t stream) {
  const float* nodes  = (const float*)d_in[0];
  const float* edges  = (const float*)d_in[1];
  const int*   rec    = (const int*)d_in[2];
  const int*   send   = (const int*)d_in[3];
  const float* anodes = (const float*)d_in[4];
  const float* aedges = (const float*)d_in[5];
  const float* Wq     = (const float*)d_in[6];
  const float* bq     = (const float*)d_in[7];
  const float* Wp     = (const float*)d_in[8];
  const float* bp     = (const float*)d_in[9];

  float* out        = (float*)d_out;
  float* out_edges  = out;                    // E*D
  float* out_nsend  = out + (size_t)EE * DD;  // E
  float* out_nrec   = out_nsend + EE;         // E
  float* out_naedge = out_nrec + EE;          // E

  char* w = (char*)d_ws;
  int*   gens     = (int*)w;                          // 32KB
  int*   gen_list = (int*)(w + 32768);                // 32KB
  int*   scal     = (int*)(w + 65536);                // 256B
  float* mask_new = (float*)(w + 65792);              // 32KB -> ends 98560
  unsigned long long* packed  = (unsigned long long*)(w + 98560);   // 8KB
  unsigned long long* partial = (unsigned long long*)(w + 106752);  // 64KB
  float* queries  = (float*)(w + 172288);             // total*DD*4 (realistic ~30KB)

  uint32_t kp0, kp1, ke0, ke1, ks0, ks1;
  tf2x32(0u, 42u, 0u, 0u, kp0, kp1);
  tf2x32(0u, 42u, 0u, 1u, ke0, ke1);
  tf2x32(0u, 42u, 0u, 2u, ks0, ks1);

  k_gens<<<NN / 256, 256, 0, stream>>>(nodes, Wp, bp, anodes, gens, kp0, kp1);
  k_scan<<<1, 256, 0, stream>>>(aedges, gens, gen_list, mask_new, out_naedge, scal,
                                packed, partial);
  k_queries<<<128, 128, 0, stream>>>(nodes, Wq, bq, gen_list, scal, queries);
  k_score<<<dim3(NN / 32, 16), 256, 0, stream>>>(nodes, anodes, queries, gen_list, scal,
                                                 packed, partial, ks0, ks1);
  k_reduce<<<256, 64, 0, stream>>>(partial, scal, packed);
  k_edges<<<(EE * DD / 4) / 256, 256, 0, stream>>>(edges, mask_new, out_edges, ke0, ke1);
  k_sendrec<<<EE / 256, 256, 0, stream>>>(send, rec, mask_new, gen_list, packed, scal,
                                          out_nsend, out_nrec);
}

// Round 6
// 47.930 us; speedup vs baseline: 9.9817x; 1.0835x over previous
//
#include <hip/hip_runtime.h>
#include <stdint.h>
#include <math.h>

#define NN 8192
#define EE 8192
#define DD 128

// modern JAX (jax_threefry_partitionable=True):
//   bits(idx) = o0 ^ o1 of threefry(key, (0, idx));
//   split -> subkey j = (o0, o1) of threefry(key, (0, j))
__host__ __device__ inline void tf2x32(uint32_t k0, uint32_t k1, uint32_t c0, uint32_t c1,
                                       uint32_t& o0, uint32_t& o1) {
  uint32_t ks[3] = {k0, k1, 0x1BD11BDAu ^ k0 ^ k1};
  uint32_t x0 = c0 + k0, x1 = c1 + k1;
  const uint32_t rot0[4] = {13u, 15u, 26u, 6u};
  const uint32_t rot1[4] = {17u, 29u, 16u, 24u};
#pragma unroll
  for (int i = 0; i < 5; ++i) {
#pragma unroll
    for (int r = 0; r < 4; ++r) {
      uint32_t d = (i & 1) ? rot1[r] : rot0[r];
      x0 += x1;
      x1 = (x1 << d) | (x1 >> (32u - d));
      x1 ^= x0;
    }
    x0 += ks[(i + 1) % 3];
    x1 += ks[(i + 2) % 3] + (uint32_t)(i + 1);
  }
  o0 = x0; o1 = x1;
}

__device__ inline uint32_t rbits32(uint32_t k0, uint32_t k1, uint32_t idx) {
  uint32_t o0, o1;
  tf2x32(k0, k1, 0u, idx, o0, o1);
  return o0 ^ o1;
}

__device__ inline float u01(uint32_t b) {
  return __uint_as_float((b >> 9) | 0x3f800000u) - 1.0f;
}

// XLA f32 erf_inv polynomial
__device__ inline float erfinv_f32(float x) {
  float w = -log1pf(-x * x);
  float p;
  if (w < 5.0f) {
    w -= 2.5f;
    p = 2.81022636e-08f;
    p = fmaf(p, w, 3.43273939e-07f);
    p = fmaf(p, w, -3.5233877e-06f);
    p = fmaf(p, w, -4.39150654e-06f);
    p = fmaf(p, w, 0.00021858087f);
    p = fmaf(p, w, -0.00125372503f);
    p = fmaf(p, w, -0.00417768164f);
    p = fmaf(p, w, 0.246640727f);
    p = fmaf(p, w, 1.50140941f);
  } else {
    w = sqrtf(w) - 3.0f;
    p = -0.000200214257f;
    p = fmaf(p, w, 0.000100950558f);
    p = fmaf(p, w, 0.00134934322f);
    p = fmaf(p, w, -0.00367342844f);
    p = fmaf(p, w, 0.00573950773f);
    p = fmaf(p, w, -0.0076224613f);
    p = fmaf(p, w, 0.00943887047f);
    p = fmaf(p, w, 1.00167406f);
    p = fmaf(p, w, 2.83297682f);
  }
  return p * x;
}

// A: per-node gen decision; 4 lanes per row for coalesced 64B segments
__global__ __launch_bounds__(256)
void k_gens(const float* __restrict__ nodes, const float* __restrict__ Wp,
            const float* __restrict__ bp, const float* __restrict__ anodes,
            int* __restrict__ gens, uint32_t kp0, uint32_t kp1) {
  int t = blockIdx.x * 256 + threadIdx.x;
  int i = t >> 2, qd = t & 3;
  if (i >= NN) return;
  const float4* row = (const float4*)(nodes + (size_t)i * DD);
  const float4* w = (const float4*)Wp;
  float acc = 0.f;
#pragma unroll
  for (int c = 0; c < 8; ++c) {
    int k4 = qd + 4 * c;
    float4 a = row[k4], b = w[k4];
    acc = fmaf(a.x, b.x, acc); acc = fmaf(a.y, b.y, acc);
    acc = fmaf(a.z, b.z, acc); acc = fmaf(a.w, b.w, acc);
  }
  acc += __shfl_xor(acc, 1, 4);
  acc += __shfl_xor(acc, 2, 4);
  if (qd == 0) {
    float prob = 1.0f / (1.0f + expf(-(acc + bp[0])));
    uint32_t b = rbits32(kp0, kp1, (uint32_t)i);
    gens[i] = (u01(b) < prob * anodes[i]) ? 1 : 0;
  }
}

// B: scans, gen_list, naedges/mask_new, zero partial accumulators
__global__ __launch_bounds__(256)
void k_scan(const float* __restrict__ aedges, const int* __restrict__ gens,
            int* __restrict__ gen_list, float* __restrict__ mask_new,
            float* __restrict__ naedges_out, int* __restrict__ scal,
            unsigned long long* __restrict__ partial) {
  __shared__ int P[EE];
  __shared__ int chunk[256];
  __shared__ int s_eact, s_total;
  int tid = threadIdx.x;
  int base = tid * 32;

  int av[32]; int aloc = 0;
  {
    const float4* a4 = (const float4*)(aedges + base);
#pragma unroll
    for (int k4 = 0; k4 < 8; ++k4) {
      float4 x = a4[k4];
      av[4 * k4 + 0] = (x.x > 0.f); av[4 * k4 + 1] = (x.y > 0.f);
      av[4 * k4 + 2] = (x.z > 0.f); av[4 * k4 + 3] = (x.w > 0.f);
    }
#pragma unroll
    for (int k = 0; k < 32; ++k) aloc += av[k];
  }
  chunk[tid] = aloc; __syncthreads();
  if (tid == 0) {
    int run = 0;
    for (int t = 0; t < 256; ++t) { int v = chunk[t]; chunk[t] = run; run += v; }
    s_eact = run;
  }
  __syncthreads();
  int e_active = s_eact;
  {
    int run = chunk[tid];
#pragma unroll
    for (int k = 0; k < 32; ++k) { run += av[k]; P[base + k] = run; }
  }

  int g[32]; int gloc = 0;
  {
    const int4* g4 = (const int4*)(gens + base);
#pragma unroll
    for (int k4 = 0; k4 < 8; ++k4) {
      int4 x = g4[k4];
      g[4 * k4 + 0] = x.x; g[4 * k4 + 1] = x.y;
      g[4 * k4 + 2] = x.z; g[4 * k4 + 3] = x.w;
    }
#pragma unroll
    for (int k = 0; k < 32; ++k) gloc += g[k];
  }
  __syncthreads();
  chunk[tid] = gloc; __syncthreads();
  if (tid == 0) {
    int run = 0;
    for (int t = 0; t < 256; ++t) { int v = chunk[t]; chunk[t] = run; run += v; }
    s_total = run;
  }
  __syncthreads();
  int total = s_total;
  {
    int rank = chunk[tid];
#pragma unroll
    for (int k = 0; k < 32; ++k) {
      if (g[k]) {
        if (e_active + rank < EE) gen_list[rank] = base + k;
        rank++;
      }
    }
  }
  if (tid == 0) { scal[0] = e_active; scal[1] = total; }

  // zero partial accumulators (total*32 slots)
  for (int idx = tid; idx < total * 32; idx += 256) partial[idx] = 0ull;

  int allowed = EE - e_active - 1;
  int n_gens = total;
  if (n_gens > allowed) n_gens = allowed;
  if (n_gens < 0) n_gens = 0;

  __syncthreads();
#pragma unroll
  for (int k = 0; k < 32; ++k) {
    int j = base + k;
    int lo = j - n_gens - 1;
    int wsum = P[j] - (lo >= 0 ? P[lo] : 0);
    float dil = (wsum > 0) ? 1.f : 0.f;
    if (j == EE - 1) dil = 0.f;
    naedges_out[j] = dil;
    mask_new[j] = dil * (1.0f - (float)av[k]);
  }
}

// C1: queries[r] = nodes[gen_list[r]] @ Wq + bq, for r < total
__global__ __launch_bounds__(128)
void k_queries(const float* __restrict__ nodes, const float* __restrict__ Wq,
               const float* __restrict__ bq, const int* __restrict__ gen_list,
               const int* __restrict__ scal, float* __restrict__ queries) {
  __shared__ float ni[DD];
  int tid = threadIdx.x;
  int total = scal[1];
  for (int r = blockIdx.x; r < total; r += gridDim.x) {
    int i = gen_list[r];
    ni[tid] = nodes[(size_t)i * DD + tid];
    __syncthreads();
    float acc = bq[tid];
    for (int k = 0; k < DD; ++k) acc = fmaf(ni[k], Wq[k * DD + tid], acc);
    queries[(size_t)r * DD + tid] = acc;
    __syncthreads();
  }
}

// C2: (node-chunk x rank-tile) score+gumbel argmax; hierarchical merge:
// block winner -> partial[r][x>>3] (8-way contention max, 32 slots/rank)
// key = order-preserving-float(v) << 32 | (NN-1-j)  -> max key == (max v, min j)
__global__ __launch_bounds__(256)
void k_score(const float* __restrict__ nodes, const float* __restrict__ anodes,
             const float* __restrict__ queries, const int* __restrict__ gen_list,
             const int* __restrict__ scal, unsigned long long* __restrict__ partial,
             uint32_t ks0, uint32_t ks1) {
  __shared__ float4 nd[32][32];   // 32 node rows, XOR-swizzled float4 cols
  __shared__ float q[8][DD];
  __shared__ float an[32];
  __shared__ int gi[8];
  int tid = threadIdx.x;
  int j0 = blockIdx.x * 32;
  int total = scal[1];
  int rt0 = blockIdx.y * 8;
  if (rt0 >= total) return;     // dead rank tile: exit before staging

  {
    int jj = tid >> 3, sub = tid & 7;
    const float4* src = (const float4*)(nodes + (size_t)(j0 + jj) * DD);
#pragma unroll
    for (int c = 0; c < 4; ++c) {
      int k4 = sub + 8 * c;
      nd[jj][k4 ^ (jj & 7)] = src[k4];
    }
    if (tid < 32) an[tid] = anodes[j0 + tid];
  }

  int rr = tid >> 5, jj = tid & 31;
  for (int rb = rt0; rb < total; rb += 8 * gridDim.y) {
    __syncthreads();
    {
      int lr = rb + (tid >> 5);
      int k4 = tid & 31;
      if (lr < total) {
        ((float4*)q[tid >> 5])[k4] = ((const float4*)(queries + (size_t)lr * DD))[k4];
        if (k4 == 0) gi[tid >> 5] = gen_list[lr];
      }
    }
    __syncthreads();

    int r = rb + rr;
    if (r < total) {
      const float4* qv = (const float4*)q[rr];
      float acc = 0.f;
#pragma unroll
      for (int k4 = 0; k4 < 32; ++k4) {
        float4 n = nd[jj][k4 ^ (jj & 7)];
        float4 qq = qv[k4];
        acc = fmaf(n.x, qq.x, acc); acc = fmaf(n.y, qq.y, acc);
        acc = fmaf(n.z, qq.z, acc); acc = fmaf(n.w, qq.w, acc);
      }
      int j = j0 + jj;
      float sc = fminf(fmaxf(acc, -1e4f), 1e4f);
      sc -= (1.0f - an[jj]) * 1e10f;
      uint32_t bidx = (uint32_t)gi[rr] * NN + (uint32_t)j;
      uint32_t b = rbits32(ks0, ks1, bidx);
      float u = fmaxf(1.17549435e-38f, u01(b));
      float gmb = -logf(-logf(u));
      float v = sc + gmb;
      int jbest = j;
#pragma unroll
      for (int m = 16; m; m >>= 1) {
        float ov = __shfl_xor(v, m, 32);
        int oj = __shfl_xor(jbest, m, 32);
        if (ov > v || (ov == v && oj < jbest)) { v = ov; jbest = oj; }
      }
      if (jj == 0) {
        uint32_t fb = __float_as_uint(v);
        fb = (fb & 0x80000000u) ? ~fb : (fb | 0x80000000u);
        unsigned long long key =
            ((unsigned long long)fb << 32) | (uint32_t)(NN - 1 - jbest);
        atomicMax(&partial[(size_t)r * 32 + (blockIdx.x >> 3)], key);
      }
    }
  }
}

// D (fused): new_edges noise + nsend/nrec with inline partial-max decode
__global__ __launch_bounds__(256)
void k_post(const float* __restrict__ edges, const float* __restrict__ mask_new,
            const int* __restrict__ send, const int* __restrict__ rec,
            const int* __restrict__ gen_list,
            const unsigned long long* __restrict__ partial,
            const int* __restrict__ scal,
            float* __restrict__ out_edges, float* __restrict__ out_nsend,
            float* __restrict__ out_nrec, uint32_t ke0, uint32_t ke1) {
  int t = blockIdx.x * 256 + threadIdx.x;   // float4 index
  int idx = t * 4;
  int e = idx >> 7;
  float m = mask_new[e];
  float4 v = ((const float4*)edges)[t];
  if (m > 0.f) {
    float* pv = &v.x;
#pragma unroll
    for (int k = 0; k < 4; ++k) {
      uint32_t b = rbits32(ke0, ke1, (uint32_t)(idx + k));
      float u = u01(b);
      float x = fmaf(u, 2.0f, -0.99999994f);
      x = fmaxf(-0.99999994f, x);
      float nrm = 1.41421354f * erfinv_f32(x);
      pv[k] += nrm * m;
    }
  }
  ((float4*)out_edges)[t] = v;

  if (t < EE) {
    int e_active = scal[0], total = scal[1];
    float mm = mask_new[t];
    float sf = (float)send[t] * (1.0f - mm);
    float rf = (float)rec[t] * (1.0f - mm);
    int r = t - e_active;
    if (r >= 0 && r < total) {
      unsigned long long best = 0ull;
      const unsigned long long* pp = partial + (size_t)r * 32;
#pragma unroll
      for (int p = 0; p < 32; ++p) { unsigned long long x = pp[p]; if (x > best) best = x; }
      int i = gen_list[r];
      int jsel = (NN - 1) - (int)(best & 0xFFFFFFFFull);
      sf += (float)i;
      rf += (float)jsel;
    }
    out_nsend[t] = (float)(int)sf;
    out_nrec[t] = (float)(int)rf;
  }
}

extern "C" void kernel_launch(void* const* d_in, const int* in_sizes, int n_in,
                              void* d_out, int out_size, void* d_ws, size_t ws_size,
                              hipStream_t stream) {
  const float* nodes  = (const float*)d_in[0];
  const float* edges  = (const float*)d_in[1];
  const int*   rec    = (const int*)d_in[2];
  const int*   send   = (const int*)d_in[3];
  const float* anodes = (const float*)d_in[4];
  const float* aedges = (const float*)d_in[5];
  const float* Wq     = (const float*)d_in[6];
  const float* bq     = (const float*)d_in[7];
  const float* Wp     = (const float*)d_in[8];
  const float* bp     = (const float*)d_in[9];

  float* out        = (float*)d_out;
  float* out_edges  = out;                    // E*D
  float* out_nsend  = out + (size_t)EE * DD;  // E
  float* out_nrec   = out_nsend + EE;         // E
  float* out_naedge = out_nrec + EE;          // E

  char* w = (char*)d_ws;
  int*   gens     = (int*)w;                          // 32KB
  int*   gen_list = (int*)(w + 32768);                // 32KB
  int*   scal     = (int*)(w + 65536);                // 256B
  float* mask_new = (float*)(w + 65792);              // 32KB -> ends 98560
  unsigned long long* partial = (unsigned long long*)(w + 98560);  // 6144*32*8 = 1.5MB
  float* queries  = (float*)(w + 98560 + 6144 * 32 * 8);           // total*DD*4

  uint32_t kp0, kp1, ke0, ke1, ks0, ks1;
  tf2x32(0u, 42u, 0u, 0u, kp0, kp1);
  tf2x32(0u, 42u, 0u, 1u, ke0, ke1);
  tf2x32(0u, 42u, 0u, 2u, ks0, ks1);

  k_gens<<<NN * 4 / 256, 256, 0, stream>>>(nodes, Wp, bp, anodes, gens, kp0, kp1);
  k_scan<<<1, 256, 0, stream>>>(aedges, gens, gen_list, mask_new, out_naedge, scal, partial);
  k_queries<<<128, 128, 0, stream>>>(nodes, Wq, bq, gen_list, scal, queries);
  k_score<<<dim3(NN / 32, 16), 256, 0, stream>>>(nodes, anodes, queries, gen_list, scal,
                                                 partial, ks0, ks1);
  k_post<<<(EE * DD / 4) / 256, 256, 0, stream>>>(edges, mask_new, send, rec, gen_list,
                                                  partial, scal, out_edges, out_nsend,
                                                  out_nrec, ke0, ke1);
}

// Round 9
// 44.805 us; speedup vs baseline: 10.6780x; 1.0698x over previous
//
#include <hip/hip_runtime.h>
#include <stdint.h>
#include <math.h>

#define NN 8192
#define EE 8192
#define DD 128

// modern JAX (jax_threefry_partitionable=True):
//   bits(idx) = o0 ^ o1 of threefry(key, (0, idx));
//   split -> subkey j = (o0, o1) of threefry(key, (0, j))
__host__ __device__ inline void tf2x32(uint32_t k0, uint32_t k1, uint32_t c0, uint32_t c1,
                                       uint32_t& o0, uint32_t& o1) {
  uint32_t ks[3] = {k0, k1, 0x1BD11BDAu ^ k0 ^ k1};
  uint32_t x0 = c0 + k0, x1 = c1 + k1;
  const uint32_t rot0[4] = {13u, 15u, 26u, 6u};
  const uint32_t rot1[4] = {17u, 29u, 16u, 24u};
#pragma unroll
  for (int i = 0; i < 5; ++i) {
#pragma unroll
    for (int r = 0; r < 4; ++r) {
      uint32_t d = (i & 1) ? rot1[r] : rot0[r];
      x0 += x1;
      x1 = (x1 << d) | (x1 >> (32u - d));
      x1 ^= x0;
    }
    x0 += ks[(i + 1) % 3];
    x1 += ks[(i + 2) % 3] + (uint32_t)(i + 1);
  }
  o0 = x0; o1 = x1;
}

__device__ inline uint32_t rbits32(uint32_t k0, uint32_t k1, uint32_t idx) {
  uint32_t o0, o1;
  tf2x32(k0, k1, 0u, idx, o0, o1);
  return o0 ^ o1;
}

__device__ inline float u01(uint32_t b) {
  return __uint_as_float((b >> 9) | 0x3f800000u) - 1.0f;
}

// XLA f32 erf_inv polynomial
__device__ inline float erfinv_f32(float x) {
  float w = -log1pf(-x * x);
  float p;
  if (w < 5.0f) {
    w -= 2.5f;
    p = 2.81022636e-08f;
    p = fmaf(p, w, 3.43273939e-07f);
    p = fmaf(p, w, -3.5233877e-06f);
    p = fmaf(p, w, -4.39150654e-06f);
    p = fmaf(p, w, 0.00021858087f);
    p = fmaf(p, w, -0.00125372503f);
    p = fmaf(p, w, -0.00417768164f);
    p = fmaf(p, w, 0.246640727f);
    p = fmaf(p, w, 1.50140941f);
  } else {
    w = sqrtf(w) - 3.0f;
    p = -0.000200214257f;
    p = fmaf(p, w, 0.000100950558f);
    p = fmaf(p, w, 0.00134934322f);
    p = fmaf(p, w, -0.00367342844f);
    p = fmaf(p, w, 0.00573950773f);
    p = fmaf(p, w, -0.0076224613f);
    p = fmaf(p, w, 0.00943887047f);
    p = fmaf(p, w, 1.00167406f);
    p = fmaf(p, w, 2.83297682f);
  }
  return p * x;
}

// A: per-node gen decision; 4 lanes per row for coalesced 64B segments
__global__ __launch_bounds__(256)
void k_gens(const float* __restrict__ nodes, const float* __restrict__ Wp,
            const float* __restrict__ bp, const float* __restrict__ anodes,
            int* __restrict__ gens, uint32_t kp0, uint32_t kp1) {
  int t = blockIdx.x * 256 + threadIdx.x;
  int i = t >> 2, qd = t & 3;
  if (i >= NN) return;
  const float4* row = (const float4*)(nodes + (size_t)i * DD);
  const float4* w = (const float4*)Wp;
  float acc = 0.f;
#pragma unroll
  for (int c = 0; c < 8; ++c) {
    int k4 = qd + 4 * c;
    float4 a = row[k4], b = w[k4];
    acc = fmaf(a.x, b.x, acc); acc = fmaf(a.y, b.y, acc);
    acc = fmaf(a.z, b.z, acc); acc = fmaf(a.w, b.w, acc);
  }
  acc += __shfl_xor(acc, 1, 4);
  acc += __shfl_xor(acc, 2, 4);
  if (qd == 0) {
    float prob = 1.0f / (1.0f + expf(-(acc + bp[0])));
    uint32_t b = rbits32(kp0, kp1, (uint32_t)i);
    gens[i] = (u01(b) < prob * anodes[i]) ? 1 : 0;
  }
}

// B: scans (wave-shuffle parallel), gen_list, naedges/mask_new, zero partials
__global__ __launch_bounds__(256)
void k_scan(const float* __restrict__ aedges, const int* __restrict__ gens,
            int* __restrict__ gen_list, float* __restrict__ mask_new,
            float* __restrict__ naedges_out, int* __restrict__ scal,
            unsigned long long* __restrict__ partial) {
  __shared__ int P[EE];     // 32KB
  __shared__ int aux[8];    // wave totals: [0..3]=aedges, [4..7]=gens
  int tid = threadIdx.x;
  int base = tid * 32;
  int lane = tid & 63, wid = tid >> 6;

  int av[32]; int aloc = 0;
  {
    const float4* a4 = (const float4*)(aedges + base);
#pragma unroll
    for (int k4 = 0; k4 < 8; ++k4) {
      float4 x = a4[k4];
      av[4 * k4 + 0] = (x.x > 0.f); av[4 * k4 + 1] = (x.y > 0.f);
      av[4 * k4 + 2] = (x.z > 0.f); av[4 * k4 + 3] = (x.w > 0.f);
    }
#pragma unroll
    for (int k = 0; k < 32; ++k) aloc += av[k];
  }
  int incl = aloc;
#pragma unroll
  for (int d = 1; d < 64; d <<= 1) {
    int o = __shfl_up(incl, d, 64);
    if (lane >= d) incl += o;
  }
  if (lane == 63) aux[wid] = incl;

  int g[32]; int gloc = 0;
  {
    const int4* g4 = (const int4*)(gens + base);
#pragma unroll
    for (int k4 = 0; k4 < 8; ++k4) {
      int4 x = g4[k4];
      g[4 * k4 + 0] = x.x; g[4 * k4 + 1] = x.y;
      g[4 * k4 + 2] = x.z; g[4 * k4 + 3] = x.w;
    }
#pragma unroll
    for (int k = 0; k < 32; ++k) gloc += g[k];
  }
  int incg = gloc;
#pragma unroll
  for (int d = 1; d < 64; d <<= 1) {
    int o = __shfl_up(incg, d, 64);
    if (lane >= d) incg += o;
  }
  if (lane == 63) aux[4 + wid] = incg;
  __syncthreads();

  int e_active = aux[0] + aux[1] + aux[2] + aux[3];
  int total = aux[4] + aux[5] + aux[6] + aux[7];
  int wpreA = 0, wpreG = 0;
  for (int ww = 0; ww < wid; ++ww) { wpreA += aux[ww]; wpreG += aux[4 + ww]; }

  {
    int run = wpreA + incl - aloc;   // exclusive prefix for this thread's chunk
#pragma unroll
    for (int k = 0; k < 32; ++k) { run += av[k]; P[base + k] = run; }
  }
  {
    int rank = wpreG + incg - gloc;
#pragma unroll
    for (int k = 0; k < 32; ++k) {
      if (g[k]) {
        if (e_active + rank < EE) gen_list[rank] = base + k;
        rank++;
      }
    }
  }
  if (tid == 0) { scal[0] = e_active; scal[1] = total; }

  // zero partial accumulators (total*32 slots)
  for (int idx = tid; idx < total * 32; idx += 256) partial[idx] = 0ull;

  int allowed = EE - e_active - 1;
  int n_gens = total;
  if (n_gens > allowed) n_gens = allowed;
  if (n_gens < 0) n_gens = 0;

  __syncthreads();   // P fully written before cross-chunk windowed reads
#pragma unroll
  for (int k = 0; k < 32; ++k) {
    int j = base + k;
    int lo = j - n_gens - 1;
    int wsum = P[j] - (lo >= 0 ? P[lo] : 0);
    float dil = (wsum > 0) ? 1.f : 0.f;
    if (j == EE - 1) dil = 0.f;
    naedges_out[j] = dil;
    mask_new[j] = dil * (1.0f - (float)av[k]);
  }
}

// C1: queries[r] = nodes[gen_list[r]] @ Wq + bq, for r < total
__global__ __launch_bounds__(128)
void k_queries(const float* __restrict__ nodes, const float* __restrict__ Wq,
               const float* __restrict__ bq, const int* __restrict__ gen_list,
               const int* __restrict__ scal, float* __restrict__ queries) {
  __shared__ float ni[DD];
  int tid = threadIdx.x;
  int total = scal[1];
  for (int r = blockIdx.x; r < total; r += gridDim.x) {
    int i = gen_list[r];
    ni[tid] = nodes[(size_t)i * DD + tid];
    __syncthreads();
    float acc = bq[tid];
    for (int k = 0; k < DD; ++k) acc = fmaf(ni[k], Wq[k * DD + tid], acc);
    queries[(size_t)r * DD + tid] = acc;
    __syncthreads();
  }
}

// C2: (node-chunk x rank-tile) score+gumbel argmax; hierarchical merge:
// block winner -> partial[r][x>>3] (8-way contention max, 32 slots/rank)
// key = order-preserving-float(v) << 32 | (NN-1-j)  -> max key == (max v, min j)
__global__ __launch_bounds__(256)
void k_score(const float* __restrict__ nodes, const float* __restrict__ anodes,
             const float* __restrict__ queries, const int* __restrict__ gen_list,
             const int* __restrict__ scal, unsigned long long* __restrict__ partial,
             uint32_t ks0, uint32_t ks1) {
  __shared__ float4 nd[32][32];   // 32 node rows, XOR-swizzled float4 cols
  __shared__ float q[8][DD];
  __shared__ float an[32];
  __shared__ int gi[8];
  int tid = threadIdx.x;
  int j0 = blockIdx.x * 32;
  int total = scal[1];
  int rt0 = blockIdx.y * 8;
  if (rt0 >= total) return;     // dead rank tile: exit before staging

  {
    int jj = tid >> 3, sub = tid & 7;
    const float4* src = (const float4*)(nodes + (size_t)(j0 + jj) * DD);
#pragma unroll
    for (int c = 0; c < 4; ++c) {
      int k4 = sub + 8 * c;
      nd[jj][k4 ^ (jj & 7)] = src[k4];
    }
    if (tid < 32) an[tid] = anodes[j0 + tid];
  }

  int rr = tid >> 5, jj = tid & 31;
  for (int rb = rt0; rb < total; rb += 8 * gridDim.y) {
    __syncthreads();
    {
      int lr = rb + (tid >> 5);
      int k4 = tid & 31;
      if (lr < total) {
        ((float4*)q[tid >> 5])[k4] = ((const float4*)(queries + (size_t)lr * DD))[k4];
        if (k4 == 0) gi[tid >> 5] = gen_list[lr];
      }
    }
    __syncthreads();

    int r = rb + rr;
    if (r < total) {
      const float4* qv = (const float4*)q[rr];
      float acc = 0.f;
#pragma unroll
      for (int k4 = 0; k4 < 32; ++k4) {
        float4 n = nd[jj][k4 ^ (jj & 7)];
        float4 qq = qv[k4];
        acc = fmaf(n.x, qq.x, acc); acc = fmaf(n.y, qq.y, acc);
        acc = fmaf(n.z, qq.z, acc); acc = fmaf(n.w, qq.w, acc);
      }
      int j = j0 + jj;
      float sc = fminf(fmaxf(acc, -1e4f), 1e4f);
      sc -= (1.0f - an[jj]) * 1e10f;
      uint32_t bidx = (uint32_t)gi[rr] * NN + (uint32_t)j;
      uint32_t b = rbits32(ks0, ks1, bidx);
      float u = fmaxf(1.17549435e-38f, u01(b));
      float gmb = -logf(-logf(u));
      float v = sc + gmb;
      int jbest = j;
#pragma unroll
      for (int m = 16; m; m >>= 1) {
        float ov = __shfl_xor(v, m, 32);
        int oj = __shfl_xor(jbest, m, 32);
        if (ov > v || (ov == v && oj < jbest)) { v = ov; jbest = oj; }
      }
      if (jj == 0) {
        uint32_t fb = __float_as_uint(v);
        fb = (fb & 0x80000000u) ? ~fb : (fb | 0x80000000u);
        unsigned long long key =
            ((unsigned long long)fb << 32) | (uint32_t)(NN - 1 - jbest);
        atomicMax(&partial[(size_t)r * 32 + (blockIdx.x >> 3)], key);
      }
    }
  }
}

// D (fused): new_edges noise + nsend/nrec with inline partial-max decode
__global__ __launch_bounds__(256)
void k_post(const float* __restrict__ edges, const float* __restrict__ mask_new,
            const int* __restrict__ send, const int* __restrict__ rec,
            const int* __restrict__ gen_list,
            const unsigned long long* __restrict__ partial,
            const int* __restrict__ scal,
            float* __restrict__ out_edges, float* __restrict__ out_nsend,
            float* __restrict__ out_nrec, uint32_t ke0, uint32_t ke1) {
  int t = blockIdx.x * 256 + threadIdx.x;   // float4 index
  int idx = t * 4;
  int e = idx >> 7;
  float m = mask_new[e];
  float4 v = ((const float4*)edges)[t];
  if (m > 0.f) {
    float* pv = &v.x;
#pragma unroll
    for (int k = 0; k < 4; ++k) {
      uint32_t b = rbits32(ke0, ke1, (uint32_t)(idx + k));
      float u = u01(b);
      float x = fmaf(u, 2.0f, -0.99999994f);
      x = fmaxf(-0.99999994f, x);
      float nrm = 1.41421354f * erfinv_f32(x);
      pv[k] += nrm * m;
    }
  }
  ((float4*)out_edges)[t] = v;

  if (t < EE) {
    int e_active = scal[0], total = scal[1];
    float mm = mask_new[t];
    float sf = (float)send[t] * (1.0f - mm);
    float rf = (float)rec[t] * (1.0f - mm);
    int r = t - e_active;
    if (r >= 0 && r < total) {
      unsigned long long best = 0ull;
      const unsigned long long* pp = partial + (size_t)r * 32;
#pragma unroll
      for (int p = 0; p < 32; ++p) { unsigned long long x = pp[p]; if (x > best) best = x; }
      int i = gen_list[r];
      int jsel = (NN - 1) - (int)(best & 0xFFFFFFFFull);
      sf += (float)i;
      rf += (float)jsel;
    }
    out_nsend[t] = (float)(int)sf;
    out_nrec[t] = (float)(int)rf;
  }
}

extern "C" void kernel_launch(void* const* d_in, const int* in_sizes, int n_in,
                              void* d_out, int out_size, void* d_ws, size_t ws_size,
                              hipStream_t stream) {
  const float* nodes  = (const float*)d_in[0];
  const float* edges  = (const float*)d_in[1];
  const int*   rec    = (const int*)d_in[2];
  const int*   send   = (const int*)d_in[3];
  const float* anodes = (const float*)d_in[4];
  const float* aedges = (const float*)d_in[5];
  const float* Wq     = (const float*)d_in[6];
  const float* bq     = (const float*)d_in[7];
  const float* Wp     = (const float*)d_in[8];
  const float* bp     = (const float*)d_in[9];

  float* out        = (float*)d_out;
  float* out_edges  = out;                    // E*D
  float* out_nsend  = out + (size_t)EE * DD;  // E
  float* out_nrec   = out_nsend + EE;         // E
  float* out_naedge = out_nrec + EE;          // E

  char* w = (char*)d_ws;
  int*   gens     = (int*)w;                          // 32KB
  int*   gen_list = (int*)(w + 32768);                // 32KB
  int*   scal     = (int*)(w + 65536);                // 256B
  float* mask_new = (float*)(w + 65792);              // 32KB -> ends 98560
  unsigned long long* partial = (unsigned long long*)(w + 98560);  // 6144*32*8 = 1.5MB
  float* queries  = (float*)(w + 98560 + 6144 * 32 * 8);           // total*DD*4

  uint32_t kp0, kp1, ke0, ke1, ks0, ks1;
  tf2x32(0u, 42u, 0u, 0u, kp0, kp1);
  tf2x32(0u, 42u, 0u, 1u, ke0, ke1);
  tf2x32(0u, 42u, 0u, 2u, ks0, ks1);

  k_gens<<<NN * 4 / 256, 256, 0, stream>>>(nodes, Wp, bp, anodes, gens, kp0, kp1);
  k_scan<<<1, 256, 0, stream>>>(aedges, gens, gen_list, mask_new, out_naedge, scal, partial);
  k_queries<<<128, 128, 0, stream>>>(nodes, Wq, bq, gen_list, scal, queries);
  k_score<<<dim3(NN / 32, 16), 256, 0, stream>>>(nodes, anodes, queries, gen_list, scal,
                                                 partial, ks0, ks1);
  k_post<<<(EE * DD / 4) / 256, 256, 0, stream>>>(edges, mask_new, send, rec, gen_list,
                                                  partial, scal, out_edges, out_nsend,
                                                  out_nrec, ke0, ke1);
}